// Round 6
// baseline (321.087 us; speedup 1.0000x reference)
//
#include <hip/hip_runtime.h>
#include <math.h>

#define B_ 4
#define C_ 64
#define M_ 8
#define H_ 224
#define W_ 224
#define N_ (H_*W_)        // 50176
#define CN_ (C_*N_)       // 3211264
#define MN_ (M_*N_)       // 401408
#define BCN_ (B_*CN_)
#define BMN_ (B_*MN_)

__device__ __forceinline__ float relu6f(float v){ return fminf(fmaxf(v,0.0f),6.0f); }
__device__ __forceinline__ float softplusf(float v){
  return v > 0.0f ? v + log1pf(expf(-v)) : log1pf(expf(v));
}

#define FMA4(A, W, X) { A.x = fmaf((W), (X).x, A.x); A.y = fmaf((W), (X).y, A.y); \
                        A.z = fmaf((W), (X).z, A.z); A.w = fmaf((W), (X).w, A.w); }

// ---------------------------------------------------------------------------
// K1: h = relu6(bn(conv1x1(x))) AND K = softplus(conv1x1(x)+kb)
// (round-0 verified version, byte-identical; VGPR=64 — do NOT add work here,
// it sits exactly at the 64-VGPR occupancy cliff)
// ---------------------------------------------------------------------------
__global__ __launch_bounds__(256) void k_fc1k(const float* __restrict__ x,
                                              const float* __restrict__ w,
                                              const float* __restrict__ bn,
                                              const float* __restrict__ kw,
                                              const float* __restrict__ kb,
                                              float* __restrict__ h,
                                              float* __restrict__ Kq)
{
  __shared__ float xsl[2*1024];   // [buf][c'(8)][px(128)]
  __shared__ float wl [2*512];    // [buf][c'(8)][oc(64)]
  __shared__ float kt [512];      // [c(64)][m(8)]
  const int tid  = threadIdx.x;
  const int b    = blockIdx.x / 392;
  const int pg   = blockIdx.x % 392;
  const int pix0 = pg*128;
  const float* xb = x + (size_t)b*CN_ + pix0;

  for (int idx = tid; idx < 512; idx += 256) {
    const int c = idx >> 3, m = idx & 7;
    kt[idx] = kw[m*64 + c];
  }

  // staging roles
  const int scp = tid >> 5;            // c' 0..7
  const int spx = (tid & 31) << 2;     // px 0,4,..,124
  const int e0 = tid*2, e1 = tid*2+1;
  const int wc0 = e0 >> 6, wo0 = e0 & 63;
  const int wc1 = e1 >> 6, wo1 = e1 & 63;

  { // stage slab 0
    const float4 xr = *(const float4*)(xb + (size_t)scp*N_ + spx);
    const float w0r = w[wo0*64 + wc0];
    const float w1r = w[wo1*64 + wc1];
    *(float4*)&xsl[scp*128 + spx] = xr;
    wl[e0] = w0r; wl[e1] = w1r;
  }
  __syncthreads();

  const int lane = tid & 63, wv_ = tid >> 6;
  const int och  = 2*wv_ + (lane >> 5);   // 0..7
  const int ocb  = och*8;
  const int px4  = (lane & 31) << 2;

  float4 ah[8];
  float4 ak = {0,0,0,0};
  #pragma unroll
  for (int i = 0; i < 8; ++i) ah[i] = make_float4(0.f,0.f,0.f,0.f);

  for (int ck = 0; ck < 8; ++ck) {
    const int cur = ck & 1, nxt = cur ^ 1;
    const float* xc = &xsl[cur*1024];
    const float* wc = &wl[cur*512];
    float4 xr; float w0r, w1r;
    if (ck < 7) {                       // issue next slab's global loads now
      const int c0n = (ck+1)*8;
      xr  = *(const float4*)(xb + (size_t)(c0n + scp)*N_ + spx);
      w0r = w[wo0*64 + c0n + wc0];
      w1r = w[wo1*64 + c0n + wc1];
    }
    #pragma unroll
    for (int cp = 0; cp < 8; ++cp) {
      const float4 xv = *(const float4*)&xc[cp*128 + px4];
      const float4 w0 = *(const float4*)&wc[cp*64 + ocb];
      const float4 w1 = *(const float4*)&wc[cp*64 + ocb + 4];
      const float kvw = kt[(ck*8+cp)*8 + och];
      FMA4(ah[0], w0.x, xv); FMA4(ah[1], w0.y, xv);
      FMA4(ah[2], w0.z, xv); FMA4(ah[3], w0.w, xv);
      FMA4(ah[4], w1.x, xv); FMA4(ah[5], w1.y, xv);
      FMA4(ah[6], w1.z, xv); FMA4(ah[7], w1.w, xv);
      FMA4(ak, kvw, xv);
    }
    if (ck < 7) {                       // park staged regs into next buffer
      *(float4*)&xsl[nxt*1024 + scp*128 + spx] = xr;
      wl[nxt*512 + e0] = w0r; wl[nxt*512 + e1] = w1r;
    }
    __syncthreads();
  }

  float* hb = h + (size_t)b*CN_ + pix0 + px4;
  #pragma unroll
  for (int o = 0; o < 8; ++o) {
    const int oc = ocb + o;
    const float inv  = bn[oc] / sqrtf(bn[192+oc] + 1e-5f);
    const float beta = bn[64+oc] - bn[128+oc]*inv;
    float4 o4;
    o4.x = relu6f(fmaf(ah[o].x, inv, beta));
    o4.y = relu6f(fmaf(ah[o].y, inv, beta));
    o4.z = relu6f(fmaf(ah[o].z, inv, beta));
    o4.w = relu6f(fmaf(ah[o].w, inv, beta));
    *(float4*)(hb + (size_t)oc*N_) = o4;
  }
  { // K row m = och
    const float kbm = kb[och];
    float4 q;
    q.x = softplusf(ak.x + kbm); q.y = softplusf(ak.y + kbm);
    q.z = softplusf(ak.z + kbm); q.w = softplusf(ak.w + kbm);
    *(float4*)(Kq + (size_t)b*MN_ + (size_t)och*N_ + pix0 + px4) = q;
  }
}

// ---------------------------------------------------------------------------
// KQ: Q = softplus(conv1x1(x, q_w) + q_b)  — dedicated streaming kernel.
// 1 px/thread, qw broadcast from LDS, 8 scalar accumulators -> ~24 VGPR,
// 784 blocks (~3/CU). This exists because folding Q into k_v/k_fc1k crosses
// the 64-VGPR occupancy cliff (round-5 post-mortem: +39us).
// ---------------------------------------------------------------------------
__global__ __launch_bounds__(256, 8) void k_q(const float* __restrict__ x,
                                              const float* __restrict__ qw,
                                              const float* __restrict__ qb,
                                              float* __restrict__ Q)
{
  __shared__ __align__(16) float qt[512];   // qt[c][m]
  const int tid = threadIdx.x;
  const int b   = blockIdx.x / 196;
  const int pg  = blockIdx.x % 196;
  const int px  = pg*256 + tid;
  const float* xb = x + (size_t)b*CN_ + px;

  for (int idx = tid; idx < 512; idx += 256) {
    const int c = idx >> 3, m = idx & 7;
    qt[idx] = qw[m*64 + c];
  }
  __syncthreads();

  float aq[8] = {0,0,0,0,0,0,0,0};
  #pragma unroll 8
  for (int c = 0; c < 64; ++c) {
    const float xv = xb[(size_t)c*N_];
    const float4 w0 = *(const float4*)&qt[c*8];
    const float4 w1 = *(const float4*)&qt[c*8+4];
    aq[0] = fmaf(w0.x, xv, aq[0]);
    aq[1] = fmaf(w0.y, xv, aq[1]);
    aq[2] = fmaf(w0.z, xv, aq[2]);
    aq[3] = fmaf(w0.w, xv, aq[3]);
    aq[4] = fmaf(w1.x, xv, aq[4]);
    aq[5] = fmaf(w1.y, xv, aq[5]);
    aq[6] = fmaf(w1.z, xv, aq[6]);
    aq[7] = fmaf(w1.w, xv, aq[7]);
  }
  float* Qb = Q + (size_t)b*MN_ + px;
  #pragma unroll
  for (int m = 0; m < 8; ++m)
    Qb[(size_t)m*N_] = softplusf(aq[m] + qb[m]);
}

// ---------------------------------------------------------------------------
// K2: s = relu6(bn1(dw5x5(h))) + relu6(bn2(dw3x3(h)))   32x32 tile per (b,c)
// (round-0 verified version, byte-identical)
// ---------------------------------------------------------------------------
__global__ __launch_bounds__(256) void k_dw(const float* __restrict__ h,
                                            const float* __restrict__ w5,
                                            const float* __restrict__ w3,
                                            const float* __restrict__ bn1,
                                            const float* __restrict__ bn2,
                                            float* __restrict__ s)
{
  __shared__ float tile[36*37];
  const int tid = threadIdx.x;
  const int blk = blockIdx.x;              // B*C*49
  const int t   = blk % 49;
  const int bc  = blk / 49;
  const int c   = bc & 63;
  const int tx0 = (t % 7) * 32;
  const int ty0 = (t / 7) * 32;
  const float* hb = h + (size_t)bc * N_;

  for (int idx = tid; idx < 1296; idx += 256) {
    const int ly = idx / 36, lx = idx - ly*36;
    const int gy = ty0 + ly - 2, gx = tx0 + lx - 2;
    float v = 0.0f;
    if (gy >= 0 && gy < H_ && gx >= 0 && gx < W_) v = hb[gy*W_ + gx];
    tile[ly*37 + lx] = v;
  }
  __syncthreads();

  float w5r[25], w3r[9];
  #pragma unroll
  for (int i = 0; i < 25; ++i) w5r[i] = w5[c*25 + i];
  #pragma unroll
  for (int i = 0; i < 9; ++i)  w3r[i] = w3[c*9 + i];
  const float inv1 = bn1[c] / sqrtf(bn1[192+c] + 1e-5f);
  const float bet1 = bn1[64+c] - bn1[128+c]*inv1;
  const float inv2 = bn2[c] / sqrtf(bn2[192+c] + 1e-5f);
  const float bet2 = bn2[64+c] - bn2[128+c]*inv2;

  const int ty  = tid >> 3;
  const int tx4 = (tid & 7) << 2;
  float a5[4] = {0,0,0,0}, a3[4] = {0,0,0,0};
  #pragma unroll
  for (int dy = 0; dy < 5; ++dy) {
    float r[8];
    #pragma unroll
    for (int i = 0; i < 8; ++i) r[i] = tile[(ty+dy)*37 + tx4 + i];
    #pragma unroll
    for (int dx = 0; dx < 5; ++dx) {
      const float wv = w5r[dy*5+dx];
      #pragma unroll
      for (int p = 0; p < 4; ++p) a5[p] = fmaf(wv, r[p+dx], a5[p]);
    }
    if (dy >= 1 && dy <= 3) {
      #pragma unroll
      for (int dx = 1; dx <= 3; ++dx) {
        const float wv = w3r[(dy-1)*3+(dx-1)];
        #pragma unroll
        for (int p = 0; p < 4; ++p) a3[p] = fmaf(wv, r[p+dx], a3[p]);
      }
    }
  }
  float* sb = s + (size_t)bc * N_ + (ty0+ty)*W_ + tx0 + tx4;
  float4 o4;
  o4.x = relu6f(fmaf(a5[0],inv1,bet1)) + relu6f(fmaf(a3[0],inv2,bet2));
  o4.y = relu6f(fmaf(a5[1],inv1,bet1)) + relu6f(fmaf(a3[1],inv2,bet2));
  o4.z = relu6f(fmaf(a5[2],inv1,bet1)) + relu6f(fmaf(a3[2],inv2,bet2));
  o4.w = relu6f(fmaf(a5[3],inv1,bet1)) + relu6f(fmaf(a3[3],inv2,bet2));
  *(float4*)sb = o4;
}

// ---------------------------------------------------------------------------
// K3: V = conv1x1(x,v_w)+v_b + relu6(bn(conv1x1(s,fc2_w)))
// (round-0 verified version, byte-identical; VGPR=64 — at the cliff, keep clean)
// ---------------------------------------------------------------------------
__global__ __launch_bounds__(256) void k_v(const float* __restrict__ x,
                                           const float* __restrict__ s,
                                           const float* __restrict__ vw,
                                           const float* __restrict__ vb,
                                           const float* __restrict__ fw,
                                           const float* __restrict__ fbn,
                                           float* __restrict__ V)
{
  __shared__ float xsl[2*1024];
  __shared__ float ssl[2*1024];
  __shared__ float wvl[2*512];
  __shared__ float wfl[2*512];
  const int tid  = threadIdx.x;
  const int b    = blockIdx.x / 392;
  const int pg   = blockIdx.x % 392;
  const int pix0 = pg*128;
  const float* xb = x + (size_t)b*CN_ + pix0;
  const float* sb = s + (size_t)b*CN_ + pix0;

  const int scp = tid >> 5;
  const int spx = (tid & 31) << 2;
  const int e0 = tid*2, e1 = tid*2+1;
  const int wc0 = e0 >> 6, wo0 = e0 & 63;
  const int wc1 = e1 >> 6, wo1 = e1 & 63;

  { // stage slab 0
    const float4 xr = *(const float4*)(xb + (size_t)scp*N_ + spx);
    const float4 sr = *(const float4*)(sb + (size_t)scp*N_ + spx);
    const float a0 = vw[wo0*64 + wc0], a1 = vw[wo1*64 + wc1];
    const float f0 = fw[wo0*64 + wc0], f1 = fw[wo1*64 + wc1];
    *(float4*)&xsl[scp*128 + spx] = xr;
    *(float4*)&ssl[scp*128 + spx] = sr;
    wvl[e0] = a0; wvl[e1] = a1;
    wfl[e0] = f0; wfl[e1] = f1;
  }
  __syncthreads();

  const int lane = tid & 63, wv_ = tid >> 6;
  const int och  = 2*wv_ + (lane >> 5);
  const int ocb  = och*8;
  const int px4  = (lane & 31) << 2;

  float4 av[8], af[8];
  #pragma unroll
  for (int i = 0; i < 8; ++i) { av[i] = make_float4(0,0,0,0); af[i] = make_float4(0,0,0,0); }

  for (int ck = 0; ck < 8; ++ck) {
    const int cur = ck & 1, nxt = cur ^ 1;
    const float* xc = &xsl[cur*1024];
    const float* sc2 = &ssl[cur*1024];
    const float* wvc = &wvl[cur*512];
    const float* wfc = &wfl[cur*512];
    float4 xr, sr; float a0r, a1r, f0r, f1r;
    if (ck < 7) {
      const int c0n = (ck+1)*8;
      xr  = *(const float4*)(xb + (size_t)(c0n + scp)*N_ + spx);
      sr  = *(const float4*)(sb + (size_t)(c0n + scp)*N_ + spx);
      a0r = vw[wo0*64 + c0n + wc0]; a1r = vw[wo1*64 + c0n + wc1];
      f0r = fw[wo0*64 + c0n + wc0]; f1r = fw[wo1*64 + c0n + wc1];
    }
    #pragma unroll
    for (int cp = 0; cp < 8; ++cp) {
      const float4 xv = *(const float4*)&xc[cp*128 + px4];
      const float4 sv = *(const float4*)&sc2[cp*128 + px4];
      const float4 wa0 = *(const float4*)&wvc[cp*64 + ocb];
      const float4 wa1 = *(const float4*)&wvc[cp*64 + ocb + 4];
      const float4 wf0 = *(const float4*)&wfc[cp*64 + ocb];
      const float4 wf1 = *(const float4*)&wfc[cp*64 + ocb + 4];
      FMA4(av[0], wa0.x, xv); FMA4(av[1], wa0.y, xv);
      FMA4(av[2], wa0.z, xv); FMA4(av[3], wa0.w, xv);
      FMA4(av[4], wa1.x, xv); FMA4(av[5], wa1.y, xv);
      FMA4(av[6], wa1.z, xv); FMA4(av[7], wa1.w, xv);
      FMA4(af[0], wf0.x, sv); FMA4(af[1], wf0.y, sv);
      FMA4(af[2], wf0.z, sv); FMA4(af[3], wf0.w, sv);
      FMA4(af[4], wf1.x, sv); FMA4(af[5], wf1.y, sv);
      FMA4(af[6], wf1.z, sv); FMA4(af[7], wf1.w, sv);
    }
    if (ck < 7) {
      *(float4*)&xsl[nxt*1024 + scp*128 + spx] = xr;
      *(float4*)&ssl[nxt*1024 + scp*128 + spx] = sr;
      wvl[nxt*512 + e0] = a0r; wvl[nxt*512 + e1] = a1r;
      wfl[nxt*512 + e0] = f0r; wfl[nxt*512 + e1] = f1r;
    }
    __syncthreads();
  }

  float* Vb = V + (size_t)b*CN_ + pix0 + px4;
  #pragma unroll
  for (int o = 0; o < 8; ++o) {
    const int oc = ocb + o;
    const float inv  = fbn[oc] / sqrtf(fbn[192+oc] + 1e-5f);
    const float beta = fbn[64+oc] - fbn[128+oc]*inv;
    const float bias = vb[oc];
    float4 o4;
    o4.x = av[o].x + bias + relu6f(fmaf(af[o].x, inv, beta));
    o4.y = av[o].y + bias + relu6f(fmaf(af[o].y, inv, beta));
    o4.z = av[o].z + bias + relu6f(fmaf(af[o].z, inv, beta));
    o4.w = av[o].w + bias + relu6f(fmaf(af[o].w, inv, beta));
    *(float4*)(Vb + (size_t)oc*N_) = o4;
  }
}

// ---------------------------------------------------------------------------
// K4: KV[b,m,c] = sum_n K[b,m,n]*V[b,c,n];  Ksum[b,m] = sum_n K[b,m,n]
// (round-3 float4 + value-halving butterfly version, verified)
// ---------------------------------------------------------------------------
__global__ __launch_bounds__(256) void k_kv(const float* __restrict__ V,
                                            const float* __restrict__ Kq,
                                            float* __restrict__ KV,
                                            float* __restrict__ Ksum)
{
  const int blk = blockIdx.x;
  const int b   = blk >> 7;
  const int rem = blk & 127;
  const int cg  = rem >> 4;
  const int ch  = rem & 15;
  const int tid = threadIdx.x;
  const int base = ch * 3136;
  const int end  = base + 3136;
  const float* Kb = Kq + (size_t)b*MN_;
  const float* Vb = V  + (size_t)b*CN_ + (size_t)(cg*8)*N_;

  float acc[64];
  #pragma unroll
  for (int i = 0; i < 64; ++i) acc[i] = 0.0f;
  float ks[8] = {0,0,0,0,0,0,0,0};

  for (int n4 = base + tid*4; n4 < end; n4 += 1024) {
    float4 kr[8];
    #pragma unroll
    for (int m2 = 0; m2 < 8; ++m2) kr[m2] = *(const float4*)(Kb + (size_t)m2*N_ + n4);
    #pragma unroll
    for (int m2 = 0; m2 < 8; ++m2)
      ks[m2] += (kr[m2].x + kr[m2].y) + (kr[m2].z + kr[m2].w);
    #pragma unroll
    for (int c8 = 0; c8 < 8; ++c8) {
      const float4 vv = *(const float4*)(Vb + (size_t)c8*N_ + n4);
      #pragma unroll
      for (int m2 = 0; m2 < 8; ++m2) {
        float t = acc[m2*8+c8];
        t = fmaf(kr[m2].x, vv.x, t);
        t = fmaf(kr[m2].y, vv.y, t);
        t = fmaf(kr[m2].z, vv.z, t);
        t = fmaf(kr[m2].w, vv.w, t);
        acc[m2*8+c8] = t;
      }
    }
  }
  const int lane = tid & 63;

  // value-halving butterfly: 64 values over 64 lanes -> 1 value/lane
  {
    int nv = 64;
    #pragma unroll
    for (int mask = 1; mask <= 32; mask <<= 1) {
      nv >>= 1;
      const bool hi = (lane & mask) != 0;
      #pragma unroll
      for (int i = 0; i < 32; ++i) {
        if (i < nv) {
          const float mine = hi ? acc[i] : acc[i+nv];
          const float th = __shfl_xor(mine, mask);
          acc[i] = (hi ? acc[i+nv] : acc[i]) + th;
        }
      }
    }
  }
  // lane holds value j = bitrev6(lane); j = m2*8 + c8
  const int j = 32*(lane & 1) + 16*((lane >> 1) & 1) + 8*((lane >> 2) & 1)
              + 4*((lane >> 3) & 1) + 2*((lane >> 4) & 1) + ((lane >> 5) & 1);
  atomicAdd(&KV[b*512 + (j >> 3)*64 + cg*8 + (j & 7)], acc[0]);

  if (cg == 0) {
    float mk = 0.0f;
    #pragma unroll
    for (int jj = 0; jj < 8; ++jj) {
      float v = ks[jj];
      v += __shfl_xor(v, 1);
      v += __shfl_xor(v, 2);
      v += __shfl_xor(v, 4);
      v += __shfl_xor(v, 8);
      v += __shfl_xor(v, 16);
      v += __shfl_xor(v, 32);
      if (lane == jj) mk = v;
    }
    if (lane < 8) atomicAdd(&Ksum[b*8 + lane], mk);
  }
}

// ---------------------------------------------------------------------------
// K5: out = x + gamma * (Q^T KV) / (Q^T (Ksum+eps)); Q precomputed by k_q.
// Single pass over x, low VGPR, no big LDS. (round-5 verified version)
// ---------------------------------------------------------------------------
__global__ __launch_bounds__(256) void k_out(const float* __restrict__ x,
                                             const float* __restrict__ Qbuf,
                                             const float* __restrict__ gamma,
                                             const float* __restrict__ KV,
                                             const float* __restrict__ Ksum,
                                             float* __restrict__ out)
{
  __shared__ __align__(16) float kvt[64*8];    // kvt[c][m]
  __shared__ float ksl[8];
  const int tid = threadIdx.x;
  const int b  = blockIdx.x / 196;
  const int pg = blockIdx.x % 196;
  const int pix0 = pg*256;
  const float* xb = x + (size_t)b*CN_ + pix0 + tid;
  const float* Qb = Qbuf + (size_t)b*MN_ + pix0 + tid;

  for (int idx = tid; idx < 512; idx += 256) {
    const int m = idx >> 6, c = idx & 63;
    kvt[c*8 + m] = KV[b*512 + idx];
  }
  if (tid < 8) ksl[tid] = Ksum[b*8 + tid] + 1e-6f;
  __syncthreads();

  float q[8];
  #pragma unroll
  for (int m = 0; m < 8; ++m) q[m] = Qb[(size_t)m*N_];   // already softplus'd
  float den = 0.0f;
  #pragma unroll
  for (int m = 0; m < 8; ++m) den = fmaf(q[m], ksl[m], den);
  const float sc = gamma[0] / den;

  float* ob = out + (size_t)b*CN_ + pix0 + tid;
  #pragma unroll 8
  for (int c = 0; c < 64; ++c) {
    const float4 k0 = *(const float4*)&kvt[c*8];
    const float4 k1 = *(const float4*)&kvt[c*8+4];
    float wv;
    wv = q[0]*k0.x;
    wv = fmaf(q[1], k0.y, wv);
    wv = fmaf(q[2], k0.z, wv);
    wv = fmaf(q[3], k0.w, wv);
    wv = fmaf(q[4], k1.x, wv);
    wv = fmaf(q[5], k1.y, wv);
    wv = fmaf(q[6], k1.z, wv);
    wv = fmaf(q[7], k1.w, wv);
    ob[(size_t)c*N_] = fmaf(sc, wv, xb[(size_t)c*N_]);
  }
}

// ---------------------------------------------------------------------------
extern "C" void kernel_launch(void* const* d_in, const int* in_sizes, int n_in,
                              void* d_out, int out_size, void* d_ws, size_t ws_size,
                              hipStream_t stream) {
  const float* x      = (const float*)d_in[0];
  const float* gamma  = (const float*)d_in[1];
  const float* q_w    = (const float*)d_in[2];
  const float* q_b    = (const float*)d_in[3];
  const float* k_w    = (const float*)d_in[4];
  const float* k_b    = (const float*)d_in[5];
  const float* v_w    = (const float*)d_in[6];
  const float* v_b    = (const float*)d_in[7];
  const float* fc1_w  = (const float*)d_in[8];
  const float* fc1_bn = (const float*)d_in[9];
  const float* c1_w   = (const float*)d_in[10];
  const float* c1_bn  = (const float*)d_in[11];
  const float* c2_w   = (const float*)d_in[12];
  const float* c2_bn  = (const float*)d_in[13];
  const float* fc2_w  = (const float*)d_in[14];
  const float* fc2_bn = (const float*)d_in[15];
  float* outp = (float*)d_out;

  float* ws   = (float*)d_ws;
  float* bufA = ws;                        // h, later reused for V
  float* bufS = ws + (size_t)BCN_;         // s
  float* bufK = ws + (size_t)2*BCN_;       // K (B*M*N)
  float* kv   = ws + (size_t)2*BCN_ + BMN_;
  float* ksum = kv + 2048;
  float* Qbuf = ksum + 32;                 // B*M*N

  hipMemsetAsync(kv, 0, (2048 + 32)*sizeof(float), stream);

  k_fc1k<<<dim3(B_*392), dim3(256), 0, stream>>>(x, fc1_w, fc1_bn, k_w, k_b, bufA, bufK);
  k_q   <<<dim3(B_*196), dim3(256), 0, stream>>>(x, q_w, q_b, Qbuf);
  k_dw  <<<dim3(B_*C_*49), dim3(256), 0, stream>>>(bufA, c1_w, c2_w, c1_bn, c2_bn, bufS);
  k_v   <<<dim3(B_*392), dim3(256), 0, stream>>>(x, bufS, v_w, v_b, fc2_w, fc2_bn, bufA);
  k_kv  <<<dim3(512), dim3(256), 0, stream>>>(bufA, bufK, kv, ksum);
  k_out <<<dim3(B_*196), dim3(256), 0, stream>>>(x, Qbuf, gamma, kv, ksum, outp);
}

// Round 7
// 315.211 us; speedup vs baseline: 1.0186x; 1.0186x over previous
//
#include <hip/hip_runtime.h>
#include <math.h>

#define B_ 4
#define C_ 64
#define M_ 8
#define H_ 224
#define W_ 224
#define N_ (H_*W_)        // 50176
#define CN_ (C_*N_)       // 3211264
#define MN_ (M_*N_)       // 401408
#define BCN_ (B_*CN_)
#define BMN_ (B_*MN_)

__device__ __forceinline__ float relu6f(float v){ return fminf(fmaxf(v,0.0f),6.0f); }
__device__ __forceinline__ float softplusf(float v){
  return v > 0.0f ? v + log1pf(expf(-v)) : log1pf(expf(v));
}

#define FMA4(A, W, X) { A.x = fmaf((W), (X).x, A.x); A.y = fmaf((W), (X).y, A.y); \
                        A.z = fmaf((W), (X).z, A.z); A.w = fmaf((W), (X).w, A.w); }

// ---------------------------------------------------------------------------
// K1: h = relu6(bn(conv1x1(x))) AND K = softplus(conv1x1(x)+kb)
// (round-0 verified version, byte-identical; VGPR=64 — do NOT add work here,
// it sits exactly at the 64-VGPR occupancy cliff)
// ---------------------------------------------------------------------------
__global__ __launch_bounds__(256) void k_fc1k(const float* __restrict__ x,
                                              const float* __restrict__ w,
                                              const float* __restrict__ bn,
                                              const float* __restrict__ kw,
                                              const float* __restrict__ kb,
                                              float* __restrict__ h,
                                              float* __restrict__ Kq)
{
  __shared__ float xsl[2*1024];   // [buf][c'(8)][px(128)]
  __shared__ float wl [2*512];    // [buf][c'(8)][oc(64)]
  __shared__ float kt [512];      // [c(64)][m(8)]
  const int tid  = threadIdx.x;
  const int b    = blockIdx.x / 392;
  const int pg   = blockIdx.x % 392;
  const int pix0 = pg*128;
  const float* xb = x + (size_t)b*CN_ + pix0;

  for (int idx = tid; idx < 512; idx += 256) {
    const int c = idx >> 3, m = idx & 7;
    kt[idx] = kw[m*64 + c];
  }

  // staging roles
  const int scp = tid >> 5;            // c' 0..7
  const int spx = (tid & 31) << 2;     // px 0,4,..,124
  const int e0 = tid*2, e1 = tid*2+1;
  const int wc0 = e0 >> 6, wo0 = e0 & 63;
  const int wc1 = e1 >> 6, wo1 = e1 & 63;

  { // stage slab 0
    const float4 xr = *(const float4*)(xb + (size_t)scp*N_ + spx);
    const float w0r = w[wo0*64 + wc0];
    const float w1r = w[wo1*64 + wc1];
    *(float4*)&xsl[scp*128 + spx] = xr;
    wl[e0] = w0r; wl[e1] = w1r;
  }
  __syncthreads();

  const int lane = tid & 63, wv_ = tid >> 6;
  const int och  = 2*wv_ + (lane >> 5);   // 0..7
  const int ocb  = och*8;
  const int px4  = (lane & 31) << 2;

  float4 ah[8];
  float4 ak = {0,0,0,0};
  #pragma unroll
  for (int i = 0; i < 8; ++i) ah[i] = make_float4(0.f,0.f,0.f,0.f);

  for (int ck = 0; ck < 8; ++ck) {
    const int cur = ck & 1, nxt = cur ^ 1;
    const float* xc = &xsl[cur*1024];
    const float* wc = &wl[cur*512];
    float4 xr; float w0r, w1r;
    if (ck < 7) {                       // issue next slab's global loads now
      const int c0n = (ck+1)*8;
      xr  = *(const float4*)(xb + (size_t)(c0n + scp)*N_ + spx);
      w0r = w[wo0*64 + c0n + wc0];
      w1r = w[wo1*64 + c0n + wc1];
    }
    #pragma unroll
    for (int cp = 0; cp < 8; ++cp) {
      const float4 xv = *(const float4*)&xc[cp*128 + px4];
      const float4 w0 = *(const float4*)&wc[cp*64 + ocb];
      const float4 w1 = *(const float4*)&wc[cp*64 + ocb + 4];
      const float kvw = kt[(ck*8+cp)*8 + och];
      FMA4(ah[0], w0.x, xv); FMA4(ah[1], w0.y, xv);
      FMA4(ah[2], w0.z, xv); FMA4(ah[3], w0.w, xv);
      FMA4(ah[4], w1.x, xv); FMA4(ah[5], w1.y, xv);
      FMA4(ah[6], w1.z, xv); FMA4(ah[7], w1.w, xv);
      FMA4(ak, kvw, xv);
    }
    if (ck < 7) {                       // park staged regs into next buffer
      *(float4*)&xsl[nxt*1024 + scp*128 + spx] = xr;
      wl[nxt*512 + e0] = w0r; wl[nxt*512 + e1] = w1r;
    }
    __syncthreads();
  }

  float* hb = h + (size_t)b*CN_ + pix0 + px4;
  #pragma unroll
  for (int o = 0; o < 8; ++o) {
    const int oc = ocb + o;
    const float inv  = bn[oc] / sqrtf(bn[192+oc] + 1e-5f);
    const float beta = bn[64+oc] - bn[128+oc]*inv;
    float4 o4;
    o4.x = relu6f(fmaf(ah[o].x, inv, beta));
    o4.y = relu6f(fmaf(ah[o].y, inv, beta));
    o4.z = relu6f(fmaf(ah[o].z, inv, beta));
    o4.w = relu6f(fmaf(ah[o].w, inv, beta));
    *(float4*)(hb + (size_t)oc*N_) = o4;
  }
  { // K row m = och
    const float kbm = kb[och];
    float4 q;
    q.x = softplusf(ak.x + kbm); q.y = softplusf(ak.y + kbm);
    q.z = softplusf(ak.z + kbm); q.w = softplusf(ak.w + kbm);
    *(float4*)(Kq + (size_t)b*MN_ + (size_t)och*N_ + pix0 + px4) = q;
  }
}

// ---------------------------------------------------------------------------
// K2: s = relu6(bn1(dw5x5(h))) + relu6(bn2(dw3x3(h)))   32x32 tile per (b,c)
// (round-0 verified version, byte-identical)
// ---------------------------------------------------------------------------
__global__ __launch_bounds__(256) void k_dw(const float* __restrict__ h,
                                            const float* __restrict__ w5,
                                            const float* __restrict__ w3,
                                            const float* __restrict__ bn1,
                                            const float* __restrict__ bn2,
                                            float* __restrict__ s)
{
  __shared__ float tile[36*37];
  const int tid = threadIdx.x;
  const int blk = blockIdx.x;              // B*C*49
  const int t   = blk % 49;
  const int bc  = blk / 49;
  const int c   = bc & 63;
  const int tx0 = (t % 7) * 32;
  const int ty0 = (t / 7) * 32;
  const float* hb = h + (size_t)bc * N_;

  for (int idx = tid; idx < 1296; idx += 256) {
    const int ly = idx / 36, lx = idx - ly*36;
    const int gy = ty0 + ly - 2, gx = tx0 + lx - 2;
    float v = 0.0f;
    if (gy >= 0 && gy < H_ && gx >= 0 && gx < W_) v = hb[gy*W_ + gx];
    tile[ly*37 + lx] = v;
  }
  __syncthreads();

  float w5r[25], w3r[9];
  #pragma unroll
  for (int i = 0; i < 25; ++i) w5r[i] = w5[c*25 + i];
  #pragma unroll
  for (int i = 0; i < 9; ++i)  w3r[i] = w3[c*9 + i];
  const float inv1 = bn1[c] / sqrtf(bn1[192+c] + 1e-5f);
  const float bet1 = bn1[64+c] - bn1[128+c]*inv1;
  const float inv2 = bn2[c] / sqrtf(bn2[192+c] + 1e-5f);
  const float bet2 = bn2[64+c] - bn2[128+c]*inv2;

  const int ty  = tid >> 3;
  const int tx4 = (tid & 7) << 2;
  float a5[4] = {0,0,0,0}, a3[4] = {0,0,0,0};
  #pragma unroll
  for (int dy = 0; dy < 5; ++dy) {
    float r[8];
    #pragma unroll
    for (int i = 0; i < 8; ++i) r[i] = tile[(ty+dy)*37 + tx4 + i];
    #pragma unroll
    for (int dx = 0; dx < 5; ++dx) {
      const float wv = w5r[dy*5+dx];
      #pragma unroll
      for (int p = 0; p < 4; ++p) a5[p] = fmaf(wv, r[p+dx], a5[p]);
    }
    if (dy >= 1 && dy <= 3) {
      #pragma unroll
      for (int dx = 1; dx <= 3; ++dx) {
        const float wv = w3r[(dy-1)*3+(dx-1)];
        #pragma unroll
        for (int p = 0; p < 4; ++p) a3[p] = fmaf(wv, r[p+dx], a3[p]);
      }
    }
  }
  float* sb = s + (size_t)bc * N_ + (ty0+ty)*W_ + tx0 + tx4;
  float4 o4;
  o4.x = relu6f(fmaf(a5[0],inv1,bet1)) + relu6f(fmaf(a3[0],inv2,bet2));
  o4.y = relu6f(fmaf(a5[1],inv1,bet1)) + relu6f(fmaf(a3[1],inv2,bet2));
  o4.z = relu6f(fmaf(a5[2],inv1,bet1)) + relu6f(fmaf(a3[2],inv2,bet2));
  o4.w = relu6f(fmaf(a5[3],inv1,bet1)) + relu6f(fmaf(a3[3],inv2,bet2));
  *(float4*)sb = o4;
}

// ---------------------------------------------------------------------------
// K3: V = conv1x1(x,v_w)+v_b + relu6(bn(conv1x1(s,fc2_w)))
// (round-0 verified version, byte-identical; VGPR=64 — at the cliff, keep clean)
// ---------------------------------------------------------------------------
__global__ __launch_bounds__(256) void k_v(const float* __restrict__ x,
                                           const float* __restrict__ s,
                                           const float* __restrict__ vw,
                                           const float* __restrict__ vb,
                                           const float* __restrict__ fw,
                                           const float* __restrict__ fbn,
                                           float* __restrict__ V)
{
  __shared__ float xsl[2*1024];
  __shared__ float ssl[2*1024];
  __shared__ float wvl[2*512];
  __shared__ float wfl[2*512];
  const int tid  = threadIdx.x;
  const int b    = blockIdx.x / 392;
  const int pg   = blockIdx.x % 392;
  const int pix0 = pg*128;
  const float* xb = x + (size_t)b*CN_ + pix0;
  const float* sb = s + (size_t)b*CN_ + pix0;

  const int scp = tid >> 5;
  const int spx = (tid & 31) << 2;
  const int e0 = tid*2, e1 = tid*2+1;
  const int wc0 = e0 >> 6, wo0 = e0 & 63;
  const int wc1 = e1 >> 6, wo1 = e1 & 63;

  { // stage slab 0
    const float4 xr = *(const float4*)(xb + (size_t)scp*N_ + spx);
    const float4 sr = *(const float4*)(sb + (size_t)scp*N_ + spx);
    const float a0 = vw[wo0*64 + wc0], a1 = vw[wo1*64 + wc1];
    const float f0 = fw[wo0*64 + wc0], f1 = fw[wo1*64 + wc1];
    *(float4*)&xsl[scp*128 + spx] = xr;
    *(float4*)&ssl[scp*128 + spx] = sr;
    wvl[e0] = a0; wvl[e1] = a1;
    wfl[e0] = f0; wfl[e1] = f1;
  }
  __syncthreads();

  const int lane = tid & 63, wv_ = tid >> 6;
  const int och  = 2*wv_ + (lane >> 5);
  const int ocb  = och*8;
  const int px4  = (lane & 31) << 2;

  float4 av[8], af[8];
  #pragma unroll
  for (int i = 0; i < 8; ++i) { av[i] = make_float4(0,0,0,0); af[i] = make_float4(0,0,0,0); }

  for (int ck = 0; ck < 8; ++ck) {
    const int cur = ck & 1, nxt = cur ^ 1;
    const float* xc = &xsl[cur*1024];
    const float* sc2 = &ssl[cur*1024];
    const float* wvc = &wvl[cur*512];
    const float* wfc = &wfl[cur*512];
    float4 xr, sr; float a0r, a1r, f0r, f1r;
    if (ck < 7) {
      const int c0n = (ck+1)*8;
      xr  = *(const float4*)(xb + (size_t)(c0n + scp)*N_ + spx);
      sr  = *(const float4*)(sb + (size_t)(c0n + scp)*N_ + spx);
      a0r = vw[wo0*64 + c0n + wc0]; a1r = vw[wo1*64 + c0n + wc1];
      f0r = fw[wo0*64 + c0n + wc0]; f1r = fw[wo1*64 + c0n + wc1];
    }
    #pragma unroll
    for (int cp = 0; cp < 8; ++cp) {
      const float4 xv = *(const float4*)&xc[cp*128 + px4];
      const float4 sv = *(const float4*)&sc2[cp*128 + px4];
      const float4 wa0 = *(const float4*)&wvc[cp*64 + ocb];
      const float4 wa1 = *(const float4*)&wvc[cp*64 + ocb + 4];
      const float4 wf0 = *(const float4*)&wfc[cp*64 + ocb];
      const float4 wf1 = *(const float4*)&wfc[cp*64 + ocb + 4];
      FMA4(av[0], wa0.x, xv); FMA4(av[1], wa0.y, xv);
      FMA4(av[2], wa0.z, xv); FMA4(av[3], wa0.w, xv);
      FMA4(av[4], wa1.x, xv); FMA4(av[5], wa1.y, xv);
      FMA4(av[6], wa1.z, xv); FMA4(av[7], wa1.w, xv);
      FMA4(af[0], wf0.x, sv); FMA4(af[1], wf0.y, sv);
      FMA4(af[2], wf0.z, sv); FMA4(af[3], wf0.w, sv);
      FMA4(af[4], wf1.x, sv); FMA4(af[5], wf1.y, sv);
      FMA4(af[6], wf1.z, sv); FMA4(af[7], wf1.w, sv);
    }
    if (ck < 7) {
      *(float4*)&xsl[nxt*1024 + scp*128 + spx] = xr;
      *(float4*)&ssl[nxt*1024 + scp*128 + spx] = sr;
      wvl[nxt*512 + e0] = a0r; wvl[nxt*512 + e1] = a1r;
      wfl[nxt*512 + e0] = f0r; wfl[nxt*512 + e1] = f1r;
    }
    __syncthreads();
  }

  float* Vb = V + (size_t)b*CN_ + pix0 + px4;
  #pragma unroll
  for (int o = 0; o < 8; ++o) {
    const int oc = ocb + o;
    const float inv  = fbn[oc] / sqrtf(fbn[192+oc] + 1e-5f);
    const float beta = fbn[64+oc] - fbn[128+oc]*inv;
    const float bias = vb[oc];
    float4 o4;
    o4.x = av[o].x + bias + relu6f(fmaf(af[o].x, inv, beta));
    o4.y = av[o].y + bias + relu6f(fmaf(af[o].y, inv, beta));
    o4.z = av[o].z + bias + relu6f(fmaf(af[o].z, inv, beta));
    o4.w = av[o].w + bias + relu6f(fmaf(af[o].w, inv, beta));
    *(float4*)(Vb + (size_t)oc*N_) = o4;
  }
}

// ---------------------------------------------------------------------------
// K4: KV[b,m,c] = sum_n K[b,m,n]*V[b,c,n];  Ksum[b,m] = sum_n K[b,m,n]
// (round-3 float4 + value-halving butterfly version, verified)
// ---------------------------------------------------------------------------
__global__ __launch_bounds__(256) void k_kv(const float* __restrict__ V,
                                            const float* __restrict__ Kq,
                                            float* __restrict__ KV,
                                            float* __restrict__ Ksum)
{
  const int blk = blockIdx.x;
  const int b   = blk >> 7;
  const int rem = blk & 127;
  const int cg  = rem >> 4;
  const int ch  = rem & 15;
  const int tid = threadIdx.x;
  const int base = ch * 3136;
  const int end  = base + 3136;
  const float* Kb = Kq + (size_t)b*MN_;
  const float* Vb = V  + (size_t)b*CN_ + (size_t)(cg*8)*N_;

  float acc[64];
  #pragma unroll
  for (int i = 0; i < 64; ++i) acc[i] = 0.0f;
  float ks[8] = {0,0,0,0,0,0,0,0};

  for (int n4 = base + tid*4; n4 < end; n4 += 1024) {
    float4 kr[8];
    #pragma unroll
    for (int m2 = 0; m2 < 8; ++m2) kr[m2] = *(const float4*)(Kb + (size_t)m2*N_ + n4);
    #pragma unroll
    for (int m2 = 0; m2 < 8; ++m2)
      ks[m2] += (kr[m2].x + kr[m2].y) + (kr[m2].z + kr[m2].w);
    #pragma unroll
    for (int c8 = 0; c8 < 8; ++c8) {
      const float4 vv = *(const float4*)(Vb + (size_t)c8*N_ + n4);
      #pragma unroll
      for (int m2 = 0; m2 < 8; ++m2) {
        float t = acc[m2*8+c8];
        t = fmaf(kr[m2].x, vv.x, t);
        t = fmaf(kr[m2].y, vv.y, t);
        t = fmaf(kr[m2].z, vv.z, t);
        t = fmaf(kr[m2].w, vv.w, t);
        acc[m2*8+c8] = t;
      }
    }
  }
  const int lane = tid & 63;

  // value-halving butterfly: 64 values over 64 lanes -> 1 value/lane
  {
    int nv = 64;
    #pragma unroll
    for (int mask = 1; mask <= 32; mask <<= 1) {
      nv >>= 1;
      const bool hi = (lane & mask) != 0;
      #pragma unroll
      for (int i = 0; i < 32; ++i) {
        if (i < nv) {
          const float mine = hi ? acc[i] : acc[i+nv];
          const float th = __shfl_xor(mine, mask);
          acc[i] = (hi ? acc[i+nv] : acc[i]) + th;
        }
      }
    }
  }
  // lane holds value j = bitrev6(lane); j = m2*8 + c8
  const int j = 32*(lane & 1) + 16*((lane >> 1) & 1) + 8*((lane >> 2) & 1)
              + 4*((lane >> 3) & 1) + 2*((lane >> 4) & 1) + ((lane >> 5) & 1);
  atomicAdd(&KV[b*512 + (j >> 3)*64 + cg*8 + (j & 7)], acc[0]);

  if (cg == 0) {
    float mk = 0.0f;
    #pragma unroll
    for (int jj = 0; jj < 8; ++jj) {
      float v = ks[jj];
      v += __shfl_xor(v, 1);
      v += __shfl_xor(v, 2);
      v += __shfl_xor(v, 4);
      v += __shfl_xor(v, 8);
      v += __shfl_xor(v, 16);
      v += __shfl_xor(v, 32);
      if (lane == jj) mk = v;
    }
    if (lane < 8) atomicAdd(&Ksum[b*8 + lane], mk);
  }
}

// ---------------------------------------------------------------------------
// K5: out = x + gamma * (Q^T KV) / (Q^T (Ksum+eps)), Q computed IN-KERNEL
// from a 32KB LDS x-stage (128 px/block). Q rides on the x read k_out does
// anyway — no separate k_q pass (round-6 lesson), no per-thread x array
// (round-4 spill), no k_v fold (round-5 VGPR cliff). LDS ~41KB -> 3-4
// blocks/CU vs round-0's 64KB/2 blocks.
// ---------------------------------------------------------------------------
__global__ __launch_bounds__(256) void k_out(const float* __restrict__ x,
                                             const float* __restrict__ qw,
                                             const float* __restrict__ qb,
                                             const float* __restrict__ gamma,
                                             const float* __restrict__ KV,
                                             const float* __restrict__ Ksum,
                                             float* __restrict__ out)
{
  __shared__ float xs[64*128];                 // 32KB  xs[c][px]
  __shared__ __align__(16) float kvt[64*8];    // kvt[c][m]
  __shared__ __align__(16) float qwt[64*8];    // qwt[c][m]
  __shared__ float qs[8][128];                 // qs[m][px] (scalar reads: 2-way, free)
  __shared__ float scl[128];
  __shared__ float ksl[8];
  const int tid = threadIdx.x;
  const int b  = blockIdx.x / 392;
  const int pg = blockIdx.x % 392;
  const int pix0 = pg*128;
  const float* xb = x + (size_t)b*CN_ + pix0;

  for (int idx = tid; idx < 512; idx += 256) {
    const int m = idx >> 6, c = idx & 63;
    kvt[c*8 + m] = KV[b*512 + idx];
    qwt[c*8 + m] = qw[idx];
  }
  if (tid < 8) ksl[tid] = Ksum[b*8 + tid] + 1e-6f;
  #pragma unroll
  for (int i = 0; i < 8; ++i) {                // stage x: 2048 float4, coalesced
    const int idx = i*256 + tid;
    const int c = idx >> 5, p4 = (idx & 31) << 2;
    const float4 v = *(const float4*)(xb + (size_t)c*N_ + p4);
    *(float4*)&xs[c*128 + p4] = v;
  }
  __syncthreads();

  if (tid < 128) {                             // Q phase: 1 px per thread
    const int px = tid;
    float q[8] = {0,0,0,0,0,0,0,0};
    #pragma unroll 8
    for (int c = 0; c < 64; ++c) {
      const float xv = xs[c*128 + px];
      const float4 w0 = *(const float4*)&qwt[c*8];
      const float4 w1 = *(const float4*)&qwt[c*8+4];
      q[0] = fmaf(w0.x, xv, q[0]);
      q[1] = fmaf(w0.y, xv, q[1]);
      q[2] = fmaf(w0.z, xv, q[2]);
      q[3] = fmaf(w0.w, xv, q[3]);
      q[4] = fmaf(w1.x, xv, q[4]);
      q[5] = fmaf(w1.y, xv, q[5]);
      q[6] = fmaf(w1.z, xv, q[6]);
      q[7] = fmaf(w1.w, xv, q[7]);
    }
    float den = 0.0f;
    #pragma unroll
    for (int m = 0; m < 8; ++m) {
      q[m] = softplusf(q[m] + qb[m]);
      den  = fmaf(q[m], ksl[m], den);
      qs[m][px] = q[m];
    }
    scl[px] = gamma[0] / den;
  }
  __syncthreads();

  float* ob = out + (size_t)b*CN_ + pix0;
  #pragma unroll
  for (int i = 0; i < 32; ++i) {               // 8192 outputs / 256 threads
    const int idx = i*256 + tid;
    const int c = idx >> 7, px = idx & 127;    // c wave-uniform -> kvt broadcast
    const float4 k0 = *(const float4*)&kvt[c*8];
    const float4 k1 = *(const float4*)&kvt[c*8+4];
    float wv;
    wv = qs[0][px]*k0.x;
    wv = fmaf(qs[1][px], k0.y, wv);
    wv = fmaf(qs[2][px], k0.z, wv);
    wv = fmaf(qs[3][px], k0.w, wv);
    wv = fmaf(qs[4][px], k1.x, wv);
    wv = fmaf(qs[5][px], k1.y, wv);
    wv = fmaf(qs[6][px], k1.z, wv);
    wv = fmaf(qs[7][px], k1.w, wv);
    ob[(size_t)c*N_ + px] = fmaf(scl[px], wv, xs[c*128 + px]);
  }
}

// ---------------------------------------------------------------------------
extern "C" void kernel_launch(void* const* d_in, const int* in_sizes, int n_in,
                              void* d_out, int out_size, void* d_ws, size_t ws_size,
                              hipStream_t stream) {
  const float* x      = (const float*)d_in[0];
  const float* gamma  = (const float*)d_in[1];
  const float* q_w    = (const float*)d_in[2];
  const float* q_b    = (const float*)d_in[3];
  const float* k_w    = (const float*)d_in[4];
  const float* k_b    = (const float*)d_in[5];
  const float* v_w    = (const float*)d_in[6];
  const float* v_b    = (const float*)d_in[7];
  const float* fc1_w  = (const float*)d_in[8];
  const float* fc1_bn = (const float*)d_in[9];
  const float* c1_w   = (const float*)d_in[10];
  const float* c1_bn  = (const float*)d_in[11];
  const float* c2_w   = (const float*)d_in[12];
  const float* c2_bn  = (const float*)d_in[13];
  const float* fc2_w  = (const float*)d_in[14];
  const float* fc2_bn = (const float*)d_in[15];
  float* outp = (float*)d_out;

  float* ws   = (float*)d_ws;
  float* bufA = ws;                        // h, later reused for V
  float* bufS = ws + (size_t)BCN_;         // s
  float* bufK = ws + (size_t)2*BCN_;       // K (B*M*N)
  float* kv   = ws + (size_t)2*BCN_ + BMN_;
  float* ksum = kv + 2048;

  hipMemsetAsync(kv, 0, (2048 + 32)*sizeof(float), stream);

  k_fc1k<<<dim3(B_*392), dim3(256), 0, stream>>>(x, fc1_w, fc1_bn, k_w, k_b, bufA, bufK);
  k_dw  <<<dim3(B_*C_*49), dim3(256), 0, stream>>>(bufA, c1_w, c2_w, c1_bn, c2_bn, bufS);
  k_v   <<<dim3(B_*392), dim3(256), 0, stream>>>(x, bufS, v_w, v_b, fc2_w, fc2_bn, bufA);
  k_kv  <<<dim3(512), dim3(256), 0, stream>>>(bufA, bufK, kv, ksum);
  k_out <<<dim3(B_*392), dim3(256), 0, stream>>>(x, q_w, q_b, gamma, kv, ksum, outp);
}

// Round 8
// 302.413 us; speedup vs baseline: 1.0618x; 1.0423x over previous
//
#include <hip/hip_runtime.h>
#include <math.h>

#define B_ 4
#define C_ 64
#define M_ 8
#define H_ 224
#define W_ 224
#define N_ (H_*W_)        // 50176
#define CN_ (C_*N_)       // 3211264
#define MN_ (M_*N_)       // 401408
#define BCN_ (B_*CN_)
#define BMN_ (B_*MN_)

typedef __attribute__((ext_vector_type(8))) short short8;       // 8 bf16
typedef __attribute__((ext_vector_type(4))) float f32x4;
typedef __attribute__((ext_vector_type(4))) unsigned int uint4v;

__device__ __forceinline__ float relu6f(float v){ return fminf(fmaxf(v,0.0f),6.0f); }
__device__ __forceinline__ float softplusf(float v){
  return v > 0.0f ? v + log1pf(expf(-v)) : log1pf(expf(v));
}
// RNE-pack two f32 -> one u32 of 2 bf16 (lo in low half)
__device__ __forceinline__ unsigned int rne2(float lo, float hi){
  unsigned int ul = __float_as_uint(lo); ul += 0x7FFFu + ((ul>>16)&1u);
  unsigned int uh = __float_as_uint(hi); uh += 0x7FFFu + ((uh>>16)&1u);
  return (ul>>16) | (uh & 0xFFFF0000u);
}

#define FMA4(A, W, X) { A.x = fmaf((W), (X).x, A.x); A.y = fmaf((W), (X).y, A.y); \
                        A.z = fmaf((W), (X).z, A.z); A.w = fmaf((W), (X).w, A.w); }

// ---------------------------------------------------------------------------
// K1: h = relu6(bn(conv1x1(x))) AND K = softplus(conv1x1(x)+kb)
// (round-0 verified version, byte-identical; VGPR=64 cliff — keep clean)
// ---------------------------------------------------------------------------
__global__ __launch_bounds__(256) void k_fc1k(const float* __restrict__ x,
                                              const float* __restrict__ w,
                                              const float* __restrict__ bn,
                                              const float* __restrict__ kw,
                                              const float* __restrict__ kb,
                                              float* __restrict__ h,
                                              float* __restrict__ Kq)
{
  __shared__ float xsl[2*1024];   // [buf][c'(8)][px(128)]
  __shared__ float wl [2*512];    // [buf][c'(8)][oc(64)]
  __shared__ float kt [512];      // [c(64)][m(8)]
  const int tid  = threadIdx.x;
  const int b    = blockIdx.x / 392;
  const int pg   = blockIdx.x % 392;
  const int pix0 = pg*128;
  const float* xb = x + (size_t)b*CN_ + pix0;

  for (int idx = tid; idx < 512; idx += 256) {
    const int c = idx >> 3, m = idx & 7;
    kt[idx] = kw[m*64 + c];
  }

  // staging roles
  const int scp = tid >> 5;            // c' 0..7
  const int spx = (tid & 31) << 2;     // px 0,4,..,124
  const int e0 = tid*2, e1 = tid*2+1;
  const int wc0 = e0 >> 6, wo0 = e0 & 63;
  const int wc1 = e1 >> 6, wo1 = e1 & 63;

  { // stage slab 0
    const float4 xr = *(const float4*)(xb + (size_t)scp*N_ + spx);
    const float w0r = w[wo0*64 + wc0];
    const float w1r = w[wo1*64 + wc1];
    *(float4*)&xsl[scp*128 + spx] = xr;
    wl[e0] = w0r; wl[e1] = w1r;
  }
  __syncthreads();

  const int lane = tid & 63, wv_ = tid >> 6;
  const int och  = 2*wv_ + (lane >> 5);   // 0..7
  const int ocb  = och*8;
  const int px4  = (lane & 31) << 2;

  float4 ah[8];
  float4 ak = {0,0,0,0};
  #pragma unroll
  for (int i = 0; i < 8; ++i) ah[i] = make_float4(0.f,0.f,0.f,0.f);

  for (int ck = 0; ck < 8; ++ck) {
    const int cur = ck & 1, nxt = cur ^ 1;
    const float* xc = &xsl[cur*1024];
    const float* wc = &wl[cur*512];
    float4 xr; float w0r, w1r;
    if (ck < 7) {                       // issue next slab's global loads now
      const int c0n = (ck+1)*8;
      xr  = *(const float4*)(xb + (size_t)(c0n + scp)*N_ + spx);
      w0r = w[wo0*64 + c0n + wc0];
      w1r = w[wo1*64 + c0n + wc1];
    }
    #pragma unroll
    for (int cp = 0; cp < 8; ++cp) {
      const float4 xv = *(const float4*)&xc[cp*128 + px4];
      const float4 w0 = *(const float4*)&wc[cp*64 + ocb];
      const float4 w1 = *(const float4*)&wc[cp*64 + ocb + 4];
      const float kvw = kt[(ck*8+cp)*8 + och];
      FMA4(ah[0], w0.x, xv); FMA4(ah[1], w0.y, xv);
      FMA4(ah[2], w0.z, xv); FMA4(ah[3], w0.w, xv);
      FMA4(ah[4], w1.x, xv); FMA4(ah[5], w1.y, xv);
      FMA4(ah[6], w1.z, xv); FMA4(ah[7], w1.w, xv);
      FMA4(ak, kvw, xv);
    }
    if (ck < 7) {                       // park staged regs into next buffer
      *(float4*)&xsl[nxt*1024 + scp*128 + spx] = xr;
      wl[nxt*512 + e0] = w0r; wl[nxt*512 + e1] = w1r;
    }
    __syncthreads();
  }

  float* hb = h + (size_t)b*CN_ + pix0 + px4;
  #pragma unroll
  for (int o = 0; o < 8; ++o) {
    const int oc = ocb + o;
    const float inv  = bn[oc] / sqrtf(bn[192+oc] + 1e-5f);
    const float beta = bn[64+oc] - bn[128+oc]*inv;
    float4 o4;
    o4.x = relu6f(fmaf(ah[o].x, inv, beta));
    o4.y = relu6f(fmaf(ah[o].y, inv, beta));
    o4.z = relu6f(fmaf(ah[o].z, inv, beta));
    o4.w = relu6f(fmaf(ah[o].w, inv, beta));
    *(float4*)(hb + (size_t)oc*N_) = o4;
  }
  { // K row m = och
    const float kbm = kb[och];
    float4 q;
    q.x = softplusf(ak.x + kbm); q.y = softplusf(ak.y + kbm);
    q.z = softplusf(ak.z + kbm); q.w = softplusf(ak.w + kbm);
    *(float4*)(Kq + (size_t)b*MN_ + (size_t)och*N_ + pix0 + px4) = q;
  }
}

// ---------------------------------------------------------------------------
// K2: s = relu6(bn1(dw5x5(h))) + relu6(bn2(dw3x3(h)))   32x32 tile per (b,c)
// (round-0 verified version, byte-identical)
// ---------------------------------------------------------------------------
__global__ __launch_bounds__(256) void k_dw(const float* __restrict__ h,
                                            const float* __restrict__ w5,
                                            const float* __restrict__ w3,
                                            const float* __restrict__ bn1,
                                            const float* __restrict__ bn2,
                                            float* __restrict__ s)
{
  __shared__ float tile[36*37];
  const int tid = threadIdx.x;
  const int blk = blockIdx.x;              // B*C*49
  const int t   = blk % 49;
  const int bc  = blk / 49;
  const int c   = bc & 63;
  const int tx0 = (t % 7) * 32;
  const int ty0 = (t / 7) * 32;
  const float* hb = h + (size_t)bc * N_;

  for (int idx = tid; idx < 1296; idx += 256) {
    const int ly = idx / 36, lx = idx - ly*36;
    const int gy = ty0 + ly - 2, gx = tx0 + lx - 2;
    float v = 0.0f;
    if (gy >= 0 && gy < H_ && gx >= 0 && gx < W_) v = hb[gy*W_ + gx];
    tile[ly*37 + lx] = v;
  }
  __syncthreads();

  float w5r[25], w3r[9];
  #pragma unroll
  for (int i = 0; i < 25; ++i) w5r[i] = w5[c*25 + i];
  #pragma unroll
  for (int i = 0; i < 9; ++i)  w3r[i] = w3[c*9 + i];
  const float inv1 = bn1[c] / sqrtf(bn1[192+c] + 1e-5f);
  const float bet1 = bn1[64+c] - bn1[128+c]*inv1;
  const float inv2 = bn2[c] / sqrtf(bn2[192+c] + 1e-5f);
  const float bet2 = bn2[64+c] - bn2[128+c]*inv2;

  const int ty  = tid >> 3;
  const int tx4 = (tid & 7) << 2;
  float a5[4] = {0,0,0,0}, a3[4] = {0,0,0,0};
  #pragma unroll
  for (int dy = 0; dy < 5; ++dy) {
    float r[8];
    #pragma unroll
    for (int i = 0; i < 8; ++i) r[i] = tile[(ty+dy)*37 + tx4 + i];
    #pragma unroll
    for (int dx = 0; dx < 5; ++dx) {
      const float wv = w5r[dy*5+dx];
      #pragma unroll
      for (int p = 0; p < 4; ++p) a5[p] = fmaf(wv, r[p+dx], a5[p]);
    }
    if (dy >= 1 && dy <= 3) {
      #pragma unroll
      for (int dx = 1; dx <= 3; ++dx) {
        const float wv = w3r[(dy-1)*3+(dx-1)];
        #pragma unroll
        for (int p = 0; p < 4; ++p) a3[p] = fmaf(wv, r[p+dx], a3[p]);
      }
    }
  }
  float* sb = s + (size_t)bc * N_ + (ty0+ty)*W_ + tx0 + tx4;
  float4 o4;
  o4.x = relu6f(fmaf(a5[0],inv1,bet1)) + relu6f(fmaf(a3[0],inv2,bet2));
  o4.y = relu6f(fmaf(a5[1],inv1,bet1)) + relu6f(fmaf(a3[1],inv2,bet2));
  o4.z = relu6f(fmaf(a5[2],inv1,bet1)) + relu6f(fmaf(a3[2],inv2,bet2));
  o4.w = relu6f(fmaf(a5[3],inv1,bet1)) + relu6f(fmaf(a3[3],inv2,bet2));
  *(float4*)sb = o4;
}

// ---------------------------------------------------------------------------
// helpers for MFMA k_v
// ---------------------------------------------------------------------------
__device__ __forceinline__ short8 bfrag(const unsigned short* __restrict__ L,
                                        int px, int c0){
  // B-frag: 8 consecutive c at one px, from bf16 LDS [c][128]
  const unsigned short* p = L + c0*128 + px;
  unsigned int w0 = (unsigned int)p[0]   | ((unsigned int)p[128]<<16);
  unsigned int w1 = (unsigned int)p[256] | ((unsigned int)p[384]<<16);
  unsigned int w2 = (unsigned int)p[512] | ((unsigned int)p[640]<<16);
  unsigned int w3 = (unsigned int)p[768] | ((unsigned int)p[896]<<16);
  uint4v q = {w0,w1,w2,w3};
  return __builtin_bit_cast(short8, q);
}
__device__ __forceinline__ short8 afrag(const float* __restrict__ W, int idx){
  // A-frag: 8 consecutive c of one oc-row, packed from fp32 global
  const float4 f0 = *(const float4*)(W + idx);
  const float4 f1 = *(const float4*)(W + idx + 4);
  uint4v q = {rne2(f0.x,f0.y), rne2(f0.z,f0.w), rne2(f1.x,f1.y), rne2(f1.z,f1.w)};
  return __builtin_bit_cast(short8, q);
}

// ---------------------------------------------------------------------------
// K3 (MFMA scout): V = conv1x1(x,v_w)+v_b + relu6(bn(conv1x1(s,fc2_w)))
// Only kernel changed this round. In-kernel bf16 LDS stage [c][128] (32KB,
// 4 blocks/CU) — no pre-pass, no bf16 global tensors, no butterfly (the
// round-3 suspects). Index maps are the round-3 numerically-validated ones:
// A row=l15(oc), k=u*8+kk*32;  B col=px, same k;  D col=l15(px),
// row=u*4+r(oc). 32 px/wave (2 subtiles), 64 oc (4 tiles), 32+32 MFMA/wave.
// ---------------------------------------------------------------------------
__global__ __launch_bounds__(256) void k_v(const float* __restrict__ x,
                                           const float* __restrict__ s,
                                           const float* __restrict__ vw,
                                           const float* __restrict__ vb,
                                           const float* __restrict__ fw,
                                           const float* __restrict__ fbn,
                                           float* __restrict__ V)
{
  __shared__ unsigned short xls[64*128];   // bf16 [c][px]  16KB
  __shared__ unsigned short sls[64*128];   // 16KB
  __shared__ float invb[3][64];
  const int tid  = threadIdx.x;
  const int b    = blockIdx.x / 392;
  const int pg   = blockIdx.x % 392;
  const int pix0 = pg*128;
  const float* xb = x + (size_t)b*CN_ + pix0;
  const float* sb = s + (size_t)b*CN_ + pix0;

  // stage all 64 channels: thread = (c-within-slab, 4-px group), 8 slabs
  const int scp = tid >> 5;
  const int spx = (tid & 31) << 2;
  #pragma unroll
  for (int i = 0; i < 8; ++i) {
    const int c = i*8 + scp;
    const float4 xr = *(const float4*)(xb + (size_t)c*N_ + spx);
    const float4 sr = *(const float4*)(sb + (size_t)c*N_ + spx);
    *(uint2*)&xls[c*128 + spx] = make_uint2(rne2(xr.x,xr.y), rne2(xr.z,xr.w));
    *(uint2*)&sls[c*128 + spx] = make_uint2(rne2(sr.x,sr.y), rne2(sr.z,sr.w));
  }
  if (tid < 64) {
    const float inv = fbn[tid] / sqrtf(fbn[192+tid] + 1e-5f);
    invb[0][tid] = inv;
    invb[1][tid] = fbn[64+tid] - fbn[128+tid]*inv;
    invb[2][tid] = vb[tid];
  }
  __syncthreads();

  const int lane = tid & 63, wv = tid >> 6;
  const int l15 = lane & 15, u = lane >> 4;
  const int pxw = wv*32;                       // wave's 32-px slice

  f32x4 av[4][2], af[4][2];
  #pragma unroll
  for (int t = 0; t < 4; ++t)
    #pragma unroll
    for (int s2 = 0; s2 < 2; ++s2) { av[t][s2] = (f32x4){0.f,0.f,0.f,0.f};
                                     af[t][s2] = (f32x4){0.f,0.f,0.f,0.f}; }

  #pragma unroll
  for (int kk = 0; kk < 2; ++kk) {
    const int c0 = kk*32 + u*8;
    // x · vw
    {
      const short8 a0 = afrag(vw, (0*16+l15)*64 + c0);
      const short8 a1 = afrag(vw, (1*16+l15)*64 + c0);
      const short8 a2 = afrag(vw, (2*16+l15)*64 + c0);
      const short8 a3 = afrag(vw, (3*16+l15)*64 + c0);
      #pragma unroll
      for (int s2 = 0; s2 < 2; ++s2) {
        const short8 bx = bfrag(xls, pxw + s2*16 + l15, c0);
        av[0][s2] = __builtin_amdgcn_mfma_f32_16x16x32_bf16(a0, bx, av[0][s2], 0,0,0);
        av[1][s2] = __builtin_amdgcn_mfma_f32_16x16x32_bf16(a1, bx, av[1][s2], 0,0,0);
        av[2][s2] = __builtin_amdgcn_mfma_f32_16x16x32_bf16(a2, bx, av[2][s2], 0,0,0);
        av[3][s2] = __builtin_amdgcn_mfma_f32_16x16x32_bf16(a3, bx, av[3][s2], 0,0,0);
      }
    }
    // s · fc2
    {
      const short8 a0 = afrag(fw, (0*16+l15)*64 + c0);
      const short8 a1 = afrag(fw, (1*16+l15)*64 + c0);
      const short8 a2 = afrag(fw, (2*16+l15)*64 + c0);
      const short8 a3 = afrag(fw, (3*16+l15)*64 + c0);
      #pragma unroll
      for (int s2 = 0; s2 < 2; ++s2) {
        const short8 bs = bfrag(sls, pxw + s2*16 + l15, c0);
        af[0][s2] = __builtin_amdgcn_mfma_f32_16x16x32_bf16(a0, bs, af[0][s2], 0,0,0);
        af[1][s2] = __builtin_amdgcn_mfma_f32_16x16x32_bf16(a1, bs, af[1][s2], 0,0,0);
        af[2][s2] = __builtin_amdgcn_mfma_f32_16x16x32_bf16(a2, bs, af[2][s2], 0,0,0);
        af[3][s2] = __builtin_amdgcn_mfma_f32_16x16x32_bf16(a3, bs, af[3][s2], 0,0,0);
      }
    }
  }

  // epilogue: V = av + vb + relu6(bn(af)); D layout col=l15(px), row=u*4+r(oc)
  float* Vb = V + (size_t)b*CN_ + pix0;
  #pragma unroll
  for (int t = 0; t < 4; ++t) {
    #pragma unroll
    for (int s2 = 0; s2 < 2; ++s2) {
      const int px = pxw + s2*16 + l15;
      #pragma unroll
      for (int r = 0; r < 4; ++r) {
        const int oc = t*16 + u*4 + r;
        Vb[(size_t)oc*N_ + px] = av[t][s2][r] + invb[2][oc]
            + relu6f(fmaf(af[t][s2][r], invb[0][oc], invb[1][oc]));
      }
    }
  }
}

// ---------------------------------------------------------------------------
// K4: KV[b,m,c] = sum_n K[b,m,n]*V[b,c,n];  Ksum[b,m] = sum_n K[b,m,n]
// (round-3 float4 + value-halving butterfly version, verified)
// ---------------------------------------------------------------------------
__global__ __launch_bounds__(256) void k_kv(const float* __restrict__ V,
                                            const float* __restrict__ Kq,
                                            float* __restrict__ KV,
                                            float* __restrict__ Ksum)
{
  const int blk = blockIdx.x;
  const int b   = blk >> 7;
  const int rem = blk & 127;
  const int cg  = rem >> 4;
  const int ch  = rem & 15;
  const int tid = threadIdx.x;
  const int base = ch * 3136;
  const int end  = base + 3136;
  const float* Kb = Kq + (size_t)b*MN_;
  const float* Vb = V  + (size_t)b*CN_ + (size_t)(cg*8)*N_;

  float acc[64];
  #pragma unroll
  for (int i = 0; i < 64; ++i) acc[i] = 0.0f;
  float ks[8] = {0,0,0,0,0,0,0,0};

  for (int n4 = base + tid*4; n4 < end; n4 += 1024) {
    float4 kr[8];
    #pragma unroll
    for (int m2 = 0; m2 < 8; ++m2) kr[m2] = *(const float4*)(Kb + (size_t)m2*N_ + n4);
    #pragma unroll
    for (int m2 = 0; m2 < 8; ++m2)
      ks[m2] += (kr[m2].x + kr[m2].y) + (kr[m2].z + kr[m2].w);
    #pragma unroll
    for (int c8 = 0; c8 < 8; ++c8) {
      const float4 vv = *(const float4*)(Vb + (size_t)c8*N_ + n4);
      #pragma unroll
      for (int m2 = 0; m2 < 8; ++m2) {
        float t = acc[m2*8+c8];
        t = fmaf(kr[m2].x, vv.x, t);
        t = fmaf(kr[m2].y, vv.y, t);
        t = fmaf(kr[m2].z, vv.z, t);
        t = fmaf(kr[m2].w, vv.w, t);
        acc[m2*8+c8] = t;
      }
    }
  }
  const int lane = tid & 63;

  // value-halving butterfly: 64 values over 64 lanes -> 1 value/lane
  {
    int nv = 64;
    #pragma unroll
    for (int mask = 1; mask <= 32; mask <<= 1) {
      nv >>= 1;
      const bool hi = (lane & mask) != 0;
      #pragma unroll
      for (int i = 0; i < 32; ++i) {
        if (i < nv) {
          const float mine = hi ? acc[i] : acc[i+nv];
          const float th = __shfl_xor(mine, mask);
          acc[i] = (hi ? acc[i+nv] : acc[i]) + th;
        }
      }
    }
  }
  // lane holds value j = bitrev6(lane); j = m2*8 + c8
  const int j = 32*(lane & 1) + 16*((lane >> 1) & 1) + 8*((lane >> 2) & 1)
              + 4*((lane >> 3) & 1) + 2*((lane >> 4) & 1) + ((lane >> 5) & 1);
  atomicAdd(&KV[b*512 + (j >> 3)*64 + cg*8 + (j & 7)], acc[0]);

  if (cg == 0) {
    float mk = 0.0f;
    #pragma unroll
    for (int jj = 0; jj < 8; ++jj) {
      float v = ks[jj];
      v += __shfl_xor(v, 1);
      v += __shfl_xor(v, 2);
      v += __shfl_xor(v, 4);
      v += __shfl_xor(v, 8);
      v += __shfl_xor(v, 16);
      v += __shfl_xor(v, 32);
      if (lane == jj) mk = v;
    }
    if (lane < 8) atomicAdd(&Ksum[b*8 + lane], mk);
  }
}

// ---------------------------------------------------------------------------
// K5: out = x + gamma * (Q^T KV) / (Q^T (Ksum+eps)), Q computed in-kernel
// from 32KB LDS x-stage. (round-7 verified version, byte-identical)
// ---------------------------------------------------------------------------
__global__ __launch_bounds__(256) void k_out(const float* __restrict__ x,
                                             const float* __restrict__ qw,
                                             const float* __restrict__ qb,
                                             const float* __restrict__ gamma,
                                             const float* __restrict__ KV,
                                             const float* __restrict__ Ksum,
                                             float* __restrict__ out)
{
  __shared__ float xs[64*128];                 // 32KB  xs[c][px]
  __shared__ __align__(16) float kvt[64*8];    // kvt[c][m]
  __shared__ __align__(16) float qwt[64*8];    // qwt[c][m]
  __shared__ float qs[8][128];
  __shared__ float scl[128];
  __shared__ float ksl[8];
  const int tid = threadIdx.x;
  const int b  = blockIdx.x / 392;
  const int pg = blockIdx.x % 392;
  const int pix0 = pg*128;
  const float* xb = x + (size_t)b*CN_ + pix0;

  for (int idx = tid; idx < 512; idx += 256) {
    const int m = idx >> 6, c = idx & 63;
    kvt[c*8 + m] = KV[b*512 + idx];
    qwt[c*8 + m] = qw[idx];
  }
  if (tid < 8) ksl[tid] = Ksum[b*8 + tid] + 1e-6f;
  #pragma unroll
  for (int i = 0; i < 8; ++i) {                // stage x: 2048 float4, coalesced
    const int idx = i*256 + tid;
    const int c = idx >> 5, p4 = (idx & 31) << 2;
    const float4 v = *(const float4*)(xb + (size_t)c*N_ + p4);
    *(float4*)&xs[c*128 + p4] = v;
  }
  __syncthreads();

  if (tid < 128) {                             // Q phase: 1 px per thread
    const int px = tid;
    float q[8] = {0,0,0,0,0,0,0,0};
    #pragma unroll 8
    for (int c = 0; c < 64; ++c) {
      const float xv = xs[c*128 + px];
      const float4 w0 = *(const float4*)&qwt[c*8];
      const float4 w1 = *(const float4*)&qwt[c*8+4];
      q[0] = fmaf(w0.x, xv, q[0]);
      q[1] = fmaf(w0.y, xv, q[1]);
      q[2] = fmaf(w0.z, xv, q[2]);
      q[3] = fmaf(w0.w, xv, q[3]);
      q[4] = fmaf(w1.x, xv, q[4]);
      q[5] = fmaf(w1.y, xv, q[5]);
      q[6] = fmaf(w1.z, xv, q[6]);
      q[7] = fmaf(w1.w, xv, q[7]);
    }
    float den = 0.0f;
    #pragma unroll
    for (int m = 0; m < 8; ++m) {
      q[m] = softplusf(q[m] + qb[m]);
      den  = fmaf(q[m], ksl[m], den);
      qs[m][px] = q[m];
    }
    scl[px] = gamma[0] / den;
  }
  __syncthreads();

  float* ob = out + (size_t)b*CN_ + pix0;
  #pragma unroll
  for (int i = 0; i < 32; ++i) {               // 8192 outputs / 256 threads
    const int idx = i*256 + tid;
    const int c = idx >> 7, px = idx & 127;
    const float4 k0 = *(const float4*)&kvt[c*8];
    const float4 k1 = *(const float4*)&kvt[c*8+4];
    float wv;
    wv = qs[0][px]*k0.x;
    wv = fmaf(qs[1][px], k0.y, wv);
    wv = fmaf(qs[2][px], k0.z, wv);
    wv = fmaf(qs[3][px], k0.w, wv);
    wv = fmaf(qs[4][px], k1.x, wv);
    wv = fmaf(qs[5][px], k1.y, wv);
    wv = fmaf(qs[6][px], k1.z, wv);
    wv = fmaf(qs[7][px], k1.w, wv);
    ob[(size_t)c*N_ + px] = fmaf(scl[px], wv, xs[c*128 + px]);
  }
}

// ---------------------------------------------------------------------------
extern "C" void kernel_launch(void* const* d_in, const int* in_sizes, int n_in,
                              void* d_out, int out_size, void* d_ws, size_t ws_size,
                              hipStream_t stream) {
  const float* x      = (const float*)d_in[0];
  const float* gamma  = (const float*)d_in[1];
  const float* q_w    = (const float*)d_in[2];
  const float* q_b    = (const float*)d_in[3];
  const float* k_w    = (const float*)d_in[4];
  const float* k_b    = (const float*)d_in[5];
  const float* v_w    = (const float*)d_in[6];
  const float* v_b    = (const float*)d_in[7];
  const float* fc1_w  = (const float*)d_in[8];
  const float* fc1_bn = (const float*)d_in[9];
  const float* c1_w   = (const float*)d_in[10];
  const float* c1_bn  = (const float*)d_in[11];
  const float* c2_w   = (const float*)d_in[12];
  const float* c2_bn  = (const float*)d_in[13];
  const float* fc2_w  = (const float*)d_in[14];
  const float* fc2_bn = (const float*)d_in[15];
  float* outp = (float*)d_out;

  float* ws   = (float*)d_ws;
  float* bufA = ws;                        // h, later reused for V
  float* bufS = ws + (size_t)BCN_;         // s
  float* bufK = ws + (size_t)2*BCN_;       // K (B*M*N)
  float* kv   = ws + (size_t)2*BCN_ + BMN_;
  float* ksum = kv + 2048;

  hipMemsetAsync(kv, 0, (2048 + 32)*sizeof(float), stream);

  k_fc1k<<<dim3(B_*392), dim3(256), 0, stream>>>(x, fc1_w, fc1_bn, k_w, k_b, bufA, bufK);
  k_dw  <<<dim3(B_*C_*49), dim3(256), 0, stream>>>(bufA, c1_w, c2_w, c1_bn, c2_bn, bufS);
  k_v   <<<dim3(B_*392), dim3(256), 0, stream>>>(x, bufS, v_w, v_b, fc2_w, fc2_bn, bufA);
  k_kv  <<<dim3(512), dim3(256), 0, stream>>>(bufA, bufK, kv, ksum);
  k_out <<<dim3(B_*392), dim3(256), 0, stream>>>(x, q_w, q_b, gamma, kv, ksum, outp);
}

// Round 10
// 301.527 us; speedup vs baseline: 1.0649x; 1.0029x over previous
//
#include <hip/hip_runtime.h>
#include <math.h>

#define B_ 4
#define C_ 64
#define M_ 8
#define H_ 224
#define W_ 224
#define N_ (H_*W_)        // 50176
#define CN_ (C_*N_)       // 3211264
#define MN_ (M_*N_)       // 401408
#define BCN_ (B_*CN_)
#define BMN_ (B_*MN_)

typedef __attribute__((ext_vector_type(8))) short short8;       // 8 bf16
typedef __attribute__((ext_vector_type(4))) float f32x4;
typedef __attribute__((ext_vector_type(4))) unsigned int uint4v;

__device__ __forceinline__ float relu6f(float v){ return fminf(fmaxf(v,0.0f),6.0f); }
__device__ __forceinline__ float softplusf(float v){
  return v > 0.0f ? v + log1pf(expf(-v)) : log1pf(expf(v));
}
// RNE-pack two f32 -> one u32 of 2 bf16 (lo in low half)
__device__ __forceinline__ unsigned int rne2(float lo, float hi){
  unsigned int ul = __float_as_uint(lo); ul += 0x7FFFu + ((ul>>16)&1u);
  unsigned int uh = __float_as_uint(hi); uh += 0x7FFFu + ((uh>>16)&1u);
  return (ul>>16) | (uh & 0xFFFF0000u);
}

// ---------------------------------------------------------------------------
// MFMA helpers (round-8 verified)
// ---------------------------------------------------------------------------
__device__ __forceinline__ short8 bfrag(const unsigned short* __restrict__ L,
                                        int px, int c0){
  // B-frag: 8 consecutive c at one px, from bf16 LDS [c][128]
  const unsigned short* p = L + c0*128 + px;
  unsigned int w0 = (unsigned int)p[0]   | ((unsigned int)p[128]<<16);
  unsigned int w1 = (unsigned int)p[256] | ((unsigned int)p[384]<<16);
  unsigned int w2 = (unsigned int)p[512] | ((unsigned int)p[640]<<16);
  unsigned int w3 = (unsigned int)p[768] | ((unsigned int)p[896]<<16);
  uint4v q = {w0,w1,w2,w3};
  return __builtin_bit_cast(short8, q);
}
__device__ __forceinline__ short8 afrag(const float* __restrict__ W, int idx){
  // A-frag: 8 consecutive c of one oc-row, packed from fp32 global
  const float4 f0 = *(const float4*)(W + idx);
  const float4 f1 = *(const float4*)(W + idx + 4);
  uint4v q = {rne2(f0.x,f0.y), rne2(f0.z,f0.w), rne2(f1.x,f1.y), rne2(f1.z,f1.w)};
  return __builtin_bit_cast(short8, q);
}
__device__ __forceinline__ short8 zfrag(){
  uint4v q = {0u,0u,0u,0u};
  return __builtin_bit_cast(short8, q);
}

// ---------------------------------------------------------------------------
// K1 (MFMA): h = relu6(bn(conv1x1(x))) AND K = softplus(conv1x1(x)+kb)
// Round-8 k_v recipe applied: in-kernel bf16 LDS stage [c][128] (16KB),
// A-frags packed from fp32 weights, B-frags gathered from LDS.
// 5 oc-tiles: 0..3 = fc1_w (h), 4 = k_w rows 0..7 + zero rows 8..15
// (round-3-validated fold). D map: col=l15(px), row=u*4+r(oc).
// ---------------------------------------------------------------------------
__global__ __launch_bounds__(256) void k_fc1k(const float* __restrict__ x,
                                              const float* __restrict__ w,
                                              const float* __restrict__ bn,
                                              const float* __restrict__ kw,
                                              const float* __restrict__ kb,
                                              float* __restrict__ h,
                                              float* __restrict__ Kq)
{
  __shared__ unsigned short xls[64*128];   // bf16 [c][px]  16KB
  __shared__ float invb[2][64];
  const int tid  = threadIdx.x;
  const int b    = blockIdx.x / 392;
  const int pg   = blockIdx.x % 392;
  const int pix0 = pg*128;
  const float* xb = x + (size_t)b*CN_ + pix0;

  // stage x: thread = (c-within-slab, 4-px group), 8 slabs
  const int scp = tid >> 5;
  const int spx = (tid & 31) << 2;
  #pragma unroll
  for (int i = 0; i < 8; ++i) {
    const int c = i*8 + scp;
    const float4 xr = *(const float4*)(xb + (size_t)c*N_ + spx);
    *(uint2*)&xls[c*128 + spx] = make_uint2(rne2(xr.x,xr.y), rne2(xr.z,xr.w));
  }
  if (tid < 64) {
    const float inv = bn[tid] / sqrtf(bn[192+tid] + 1e-5f);
    invb[0][tid] = inv;
    invb[1][tid] = bn[64+tid] - bn[128+tid]*inv;
  }
  __syncthreads();

  const int lane = tid & 63, wv = tid >> 6;
  const int l15 = lane & 15, u = lane >> 4;
  const int pxw = wv*32;                       // wave's 32-px slice

  f32x4 acc[5][2];
  #pragma unroll
  for (int t = 0; t < 5; ++t)
    #pragma unroll
    for (int s2 = 0; s2 < 2; ++s2) acc[t][s2] = (f32x4){0.f,0.f,0.f,0.f};

  #pragma unroll
  for (int kk = 0; kk < 2; ++kk) {
    const int c0 = kk*32 + u*8;
    const short8 a0 = afrag(w, (0*16+l15)*64 + c0);
    const short8 a1 = afrag(w, (1*16+l15)*64 + c0);
    const short8 a2 = afrag(w, (2*16+l15)*64 + c0);
    const short8 a3 = afrag(w, (3*16+l15)*64 + c0);
    const short8 a4 = (l15 < 8) ? afrag(kw, l15*64 + c0) : zfrag();
    #pragma unroll
    for (int s2 = 0; s2 < 2; ++s2) {
      const short8 bx = bfrag(xls, pxw + s2*16 + l15, c0);
      acc[0][s2] = __builtin_amdgcn_mfma_f32_16x16x32_bf16(a0, bx, acc[0][s2], 0,0,0);
      acc[1][s2] = __builtin_amdgcn_mfma_f32_16x16x32_bf16(a1, bx, acc[1][s2], 0,0,0);
      acc[2][s2] = __builtin_amdgcn_mfma_f32_16x16x32_bf16(a2, bx, acc[2][s2], 0,0,0);
      acc[3][s2] = __builtin_amdgcn_mfma_f32_16x16x32_bf16(a3, bx, acc[3][s2], 0,0,0);
      acc[4][s2] = __builtin_amdgcn_mfma_f32_16x16x32_bf16(a4, bx, acc[4][s2], 0,0,0);
    }
  }

  // h epilogue (tiles 0..3): D col=l15(px), row=u*4+r(oc within tile)
  float* hb = h + (size_t)b*CN_ + pix0;
  #pragma unroll
  for (int t = 0; t < 4; ++t) {
    #pragma unroll
    for (int s2 = 0; s2 < 2; ++s2) {
      const int px = pxw + s2*16 + l15;
      #pragma unroll
      for (int r = 0; r < 4; ++r) {
        const int oc = t*16 + u*4 + r;
        hb[(size_t)oc*N_ + px] = relu6f(fmaf(acc[t][s2][r], invb[0][oc], invb[1][oc]));
      }
    }
  }
  // K epilogue (tile 4, valid rows 0..7 -> u<2): m = u*4+r
  if (u < 2) {
    float* Kb = Kq + (size_t)b*MN_ + pix0;
    #pragma unroll
    for (int s2 = 0; s2 < 2; ++s2) {
      const int px = pxw + s2*16 + l15;
      #pragma unroll
      for (int r = 0; r < 4; ++r) {
        const int m = u*4 + r;
        Kb[(size_t)m*N_ + px] = softplusf(acc[4][s2][r] + kb[m]);
      }
    }
  }
}

// ---------------------------------------------------------------------------
// K2: s = relu6(bn1(dw5x5(h))) + relu6(bn2(dw3x3(h)))   32x32 tile per (b,c)
// (round-0 verified version, byte-identical)
// ---------------------------------------------------------------------------
__global__ __launch_bounds__(256) void k_dw(const float* __restrict__ h,
                                            const float* __restrict__ w5,
                                            const float* __restrict__ w3,
                                            const float* __restrict__ bn1,
                                            const float* __restrict__ bn2,
                                            float* __restrict__ s)
{
  __shared__ float tile[36*37];
  const int tid = threadIdx.x;
  const int blk = blockIdx.x;              // B*C*49
  const int t   = blk % 49;
  const int bc  = blk / 49;
  const int c   = bc & 63;
  const int tx0 = (t % 7) * 32;
  const int ty0 = (t / 7) * 32;
  const float* hb = h + (size_t)bc * N_;

  for (int idx = tid; idx < 1296; idx += 256) {
    const int ly = idx / 36, lx = idx - ly*36;
    const int gy = ty0 + ly - 2, gx = tx0 + lx - 2;
    float v = 0.0f;
    if (gy >= 0 && gy < H_ && gx >= 0 && gx < W_) v = hb[gy*W_ + gx];
    tile[ly*37 + lx] = v;
  }
  __syncthreads();

  float w5r[25], w3r[9];
  #pragma unroll
  for (int i = 0; i < 25; ++i) w5r[i] = w5[c*25 + i];
  #pragma unroll
  for (int i = 0; i < 9; ++i)  w3r[i] = w3[c*9 + i];
  const float inv1 = bn1[c] / sqrtf(bn1[192+c] + 1e-5f);
  const float bet1 = bn1[64+c] - bn1[128+c]*inv1;
  const float inv2 = bn2[c] / sqrtf(bn2[192+c] + 1e-5f);
  const float bet2 = bn2[64+c] - bn2[128+c]*inv2;

  const int ty  = tid >> 3;
  const int tx4 = (tid & 7) << 2;
  float a5[4] = {0,0,0,0}, a3[4] = {0,0,0,0};
  #pragma unroll
  for (int dy = 0; dy < 5; ++dy) {
    float r[8];
    #pragma unroll
    for (int i = 0; i < 8; ++i) r[i] = tile[(ty+dy)*37 + tx4 + i];
    #pragma unroll
    for (int dx = 0; dx < 5; ++dx) {
      const float wv = w5r[dy*5+dx];
      #pragma unroll
      for (int p = 0; p < 4; ++p) a5[p] = fmaf(wv, r[p+dx], a5[p]);
    }
    if (dy >= 1 && dy <= 3) {
      #pragma unroll
      for (int dx = 1; dx <= 3; ++dx) {
        const float wv = w3r[(dy-1)*3+(dx-1)];
        #pragma unroll
        for (int p = 0; p < 4; ++p) a3[p] = fmaf(wv, r[p+dx], a3[p]);
      }
    }
  }
  float* sb = s + (size_t)bc * N_ + (ty0+ty)*W_ + tx0 + tx4;
  float4 o4;
  o4.x = relu6f(fmaf(a5[0],inv1,bet1)) + relu6f(fmaf(a3[0],inv2,bet2));
  o4.y = relu6f(fmaf(a5[1],inv1,bet1)) + relu6f(fmaf(a3[1],inv2,bet2));
  o4.z = relu6f(fmaf(a5[2],inv1,bet1)) + relu6f(fmaf(a3[2],inv2,bet2));
  o4.w = relu6f(fmaf(a5[3],inv1,bet1)) + relu6f(fmaf(a3[3],inv2,bet2));
  *(float4*)sb = o4;
}

// ---------------------------------------------------------------------------
// K3 (MFMA, round-8 verified): V = conv1x1(x,v_w)+v_b + relu6(bn(conv1x1(s,fc2_w)))
// ---------------------------------------------------------------------------
__global__ __launch_bounds__(256) void k_v(const float* __restrict__ x,
                                           const float* __restrict__ s,
                                           const float* __restrict__ vw,
                                           const float* __restrict__ vb,
                                           const float* __restrict__ fw,
                                           const float* __restrict__ fbn,
                                           float* __restrict__ V)
{
  __shared__ unsigned short xls[64*128];   // bf16 [c][px]  16KB
  __shared__ unsigned short sls[64*128];   // 16KB
  __shared__ float invb[3][64];
  const int tid  = threadIdx.x;
  const int b    = blockIdx.x / 392;
  const int pg   = blockIdx.x % 392;
  const int pix0 = pg*128;
  const float* xb = x + (size_t)b*CN_ + pix0;
  const float* sb = s + (size_t)b*CN_ + pix0;

  // stage all 64 channels: thread = (c-within-slab, 4-px group), 8 slabs
  const int scp = tid >> 5;
  const int spx = (tid & 31) << 2;
  #pragma unroll
  for (int i = 0; i < 8; ++i) {
    const int c = i*8 + scp;
    const float4 xr = *(const float4*)(xb + (size_t)c*N_ + spx);
    const float4 sr = *(const float4*)(sb + (size_t)c*N_ + spx);
    *(uint2*)&xls[c*128 + spx] = make_uint2(rne2(xr.x,xr.y), rne2(xr.z,xr.w));
    *(uint2*)&sls[c*128 + spx] = make_uint2(rne2(sr.x,sr.y), rne2(sr.z,sr.w));
  }
  if (tid < 64) {
    const float inv = fbn[tid] / sqrtf(fbn[192+tid] + 1e-5f);
    invb[0][tid] = inv;
    invb[1][tid] = fbn[64+tid] - fbn[128+tid]*inv;
    invb[2][tid] = vb[tid];
  }
  __syncthreads();

  const int lane = tid & 63, wv = tid >> 6;
  const int l15 = lane & 15, u = lane >> 4;
  const int pxw = wv*32;                       // wave's 32-px slice

  f32x4 av[4][2], af[4][2];
  #pragma unroll
  for (int t = 0; t < 4; ++t)
    #pragma unroll
    for (int s2 = 0; s2 < 2; ++s2) { av[t][s2] = (f32x4){0.f,0.f,0.f,0.f};
                                     af[t][s2] = (f32x4){0.f,0.f,0.f,0.f}; }

  #pragma unroll
  for (int kk = 0; kk < 2; ++kk) {
    const int c0 = kk*32 + u*8;
    // x · vw
    {
      const short8 a0 = afrag(vw, (0*16+l15)*64 + c0);
      const short8 a1 = afrag(vw, (1*16+l15)*64 + c0);
      const short8 a2 = afrag(vw, (2*16+l15)*64 + c0);
      const short8 a3 = afrag(vw, (3*16+l15)*64 + c0);
      #pragma unroll
      for (int s2 = 0; s2 < 2; ++s2) {
        const short8 bx = bfrag(xls, pxw + s2*16 + l15, c0);
        av[0][s2] = __builtin_amdgcn_mfma_f32_16x16x32_bf16(a0, bx, av[0][s2], 0,0,0);
        av[1][s2] = __builtin_amdgcn_mfma_f32_16x16x32_bf16(a1, bx, av[1][s2], 0,0,0);
        av[2][s2] = __builtin_amdgcn_mfma_f32_16x16x32_bf16(a2, bx, av[2][s2], 0,0,0);
        av[3][s2] = __builtin_amdgcn_mfma_f32_16x16x32_bf16(a3, bx, av[3][s2], 0,0,0);
      }
    }
    // s · fc2
    {
      const short8 a0 = afrag(fw, (0*16+l15)*64 + c0);
      const short8 a1 = afrag(fw, (1*16+l15)*64 + c0);
      const short8 a2 = afrag(fw, (2*16+l15)*64 + c0);
      const short8 a3 = afrag(fw, (3*16+l15)*64 + c0);
      #pragma unroll
      for (int s2 = 0; s2 < 2; ++s2) {
        const short8 bs = bfrag(sls, pxw + s2*16 + l15, c0);
        af[0][s2] = __builtin_amdgcn_mfma_f32_16x16x32_bf16(a0, bs, af[0][s2], 0,0,0);
        af[1][s2] = __builtin_amdgcn_mfma_f32_16x16x32_bf16(a1, bs, af[1][s2], 0,0,0);
        af[2][s2] = __builtin_amdgcn_mfma_f32_16x16x32_bf16(a2, bs, af[2][s2], 0,0,0);
        af[3][s2] = __builtin_amdgcn_mfma_f32_16x16x32_bf16(a3, bs, af[3][s2], 0,0,0);
      }
    }
  }

  // epilogue: V = av + vb + relu6(bn(af)); D layout col=l15(px), row=u*4+r(oc)
  float* Vb = V + (size_t)b*CN_ + pix0;
  #pragma unroll
  for (int t = 0; t < 4; ++t) {
    #pragma unroll
    for (int s2 = 0; s2 < 2; ++s2) {
      const int px = pxw + s2*16 + l15;
      #pragma unroll
      for (int r = 0; r < 4; ++r) {
        const int oc = t*16 + u*4 + r;
        Vb[(size_t)oc*N_ + px] = av[t][s2][r] + invb[2][oc]
            + relu6f(fmaf(af[t][s2][r], invb[0][oc], invb[1][oc]));
      }
    }
  }
}

// ---------------------------------------------------------------------------
// K4: KV[b,m,c] = sum_n K[b,m,n]*V[b,c,n];  Ksum[b,m] = sum_n K[b,m,n]
// (round-3 float4 + value-halving butterfly version, verified)
// ---------------------------------------------------------------------------
__global__ __launch_bounds__(256) void k_kv(const float* __restrict__ V,
                                            const float* __restrict__ Kq,
                                            float* __restrict__ KV,
                                            float* __restrict__ Ksum)
{
  const int blk = blockIdx.x;
  const int b   = blk >> 7;
  const int rem = blk & 127;
  const int cg  = rem >> 4;
  const int ch  = rem & 15;
  const int tid = threadIdx.x;
  const int base = ch * 3136;
  const int end  = base + 3136;
  const float* Kb = Kq + (size_t)b*MN_;
  const float* Vb = V  + (size_t)b*CN_ + (size_t)(cg*8)*N_;

  float acc[64];
  #pragma unroll
  for (int i = 0; i < 64; ++i) acc[i] = 0.0f;
  float ks[8] = {0,0,0,0,0,0,0,0};

  for (int n4 = base + tid*4; n4 < end; n4 += 1024) {
    float4 kr[8];
    #pragma unroll
    for (int m2 = 0; m2 < 8; ++m2) kr[m2] = *(const float4*)(Kb + (size_t)m2*N_ + n4);
    #pragma unroll
    for (int m2 = 0; m2 < 8; ++m2)
      ks[m2] += (kr[m2].x + kr[m2].y) + (kr[m2].z + kr[m2].w);
    #pragma unroll
    for (int c8 = 0; c8 < 8; ++c8) {
      const float4 vv = *(const float4*)(Vb + (size_t)c8*N_ + n4);
      #pragma unroll
      for (int m2 = 0; m2 < 8; ++m2) {
        float t = acc[m2*8+c8];
        t = fmaf(kr[m2].x, vv.x, t);
        t = fmaf(kr[m2].y, vv.y, t);
        t = fmaf(kr[m2].z, vv.z, t);
        t = fmaf(kr[m2].w, vv.w, t);
        acc[m2*8+c8] = t;
      }
    }
  }
  const int lane = tid & 63;

  // value-halving butterfly: 64 values over 64 lanes -> 1 value/lane
  {
    int nv = 64;
    #pragma unroll
    for (int mask = 1; mask <= 32; mask <<= 1) {
      nv >>= 1;
      const bool hi = (lane & mask) != 0;
      #pragma unroll
      for (int i = 0; i < 32; ++i) {
        if (i < nv) {
          const float mine = hi ? acc[i] : acc[i+nv];
          const float th = __shfl_xor(mine, mask);
          acc[i] = (hi ? acc[i+nv] : acc[i]) + th;
        }
      }
    }
  }
  // lane holds value j = bitrev6(lane); j = m2*8 + c8
  const int j = 32*(lane & 1) + 16*((lane >> 1) & 1) + 8*((lane >> 2) & 1)
              + 4*((lane >> 3) & 1) + 2*((lane >> 4) & 1) + ((lane >> 5) & 1);
  atomicAdd(&KV[b*512 + (j >> 3)*64 + cg*8 + (j & 7)], acc[0]);

  if (cg == 0) {
    float mk = 0.0f;
    #pragma unroll
    for (int jj = 0; jj < 8; ++jj) {
      float v = ks[jj];
      v += __shfl_xor(v, 1);
      v += __shfl_xor(v, 2);
      v += __shfl_xor(v, 4);
      v += __shfl_xor(v, 8);
      v += __shfl_xor(v, 16);
      v += __shfl_xor(v, 32);
      if (lane == jj) mk = v;
    }
    if (lane < 8) atomicAdd(&Ksum[b*8 + lane], mk);
  }
}

// ---------------------------------------------------------------------------
// K5: out = x + gamma * (Q^T KV) / (Q^T (Ksum+eps)), Q computed in-kernel
// from 32KB LDS x-stage. (round-7 verified version, byte-identical)
// ---------------------------------------------------------------------------
__global__ __launch_bounds__(256) void k_out(const float* __restrict__ x,
                                             const float* __restrict__ qw,
                                             const float* __restrict__ qb,
                                             const float* __restrict__ gamma,
                                             const float* __restrict__ KV,
                                             const float* __restrict__ Ksum,
                                             float* __restrict__ out)
{
  __shared__ float xs[64*128];                 // 32KB  xs[c][px]
  __shared__ __align__(16) float kvt[64*8];    // kvt[c][m]
  __shared__ __align__(16) float qwt[64*8];    // qwt[c][m]
  __shared__ float qs[8][128];
  __shared__ float scl[128];
  __shared__ float ksl[8];
  const int tid = threadIdx.x;
  const int b  = blockIdx.x / 392;
  const int pg = blockIdx.x % 392;
  const int pix0 = pg*128;
  const float* xb = x + (size_t)b*CN_ + pix0;

  for (int idx = tid; idx < 512; idx += 256) {
    const int m = idx >> 6, c = idx & 63;
    kvt[c*8 + m] = KV[b*512 + idx];
    qwt[c*8 + m] = qw[idx];
  }
  if (tid < 8) ksl[tid] = Ksum[b*8 + tid] + 1e-6f;
  #pragma unroll
  for (int i = 0; i < 8; ++i) {                // stage x: 2048 float4, coalesced
    const int idx = i*256 + tid;
    const int c = idx >> 5, p4 = (idx & 31) << 2;
    const float4 v = *(const float4*)(xb + (size_t)c*N_ + p4);
    *(float4*)&xs[c*128 + p4] = v;
  }
  __syncthreads();

  if (tid < 128) {                             // Q phase: 1 px per thread
    const int px = tid;
    float q[8] = {0,0,0,0,0,0,0,0};
    #pragma unroll 8
    for (int c = 0; c < 64; ++c) {
      const float xv = xs[c*128 + px];
      const float4 w0 = *(const float4*)&qwt[c*8];
      const float4 w1 = *(const float4*)&qwt[c*8+4];
      q[0] = fmaf(w0.x, xv, q[0]);
      q[1] = fmaf(w0.y, xv, q[1]);
      q[2] = fmaf(w0.z, xv, q[2]);
      q[3] = fmaf(w0.w, xv, q[3]);
      q[4] = fmaf(w1.x, xv, q[4]);
      q[5] = fmaf(w1.y, xv, q[5]);
      q[6] = fmaf(w1.z, xv, q[6]);
      q[7] = fmaf(w1.w, xv, q[7]);
    }
    float den = 0.0f;
    #pragma unroll
    for (int m = 0; m < 8; ++m) {
      q[m] = softplusf(q[m] + qb[m]);
      den  = fmaf(q[m], ksl[m], den);
      qs[m][px] = q[m];
    }
    scl[px] = gamma[0] / den;
  }
  __syncthreads();

  float* ob = out + (size_t)b*CN_ + pix0;
  #pragma unroll
  for (int i = 0; i < 32; ++i) {               // 8192 outputs / 256 threads
    const int idx = i*256 + tid;
    const int c = idx >> 7, px = idx & 127;
    const float4 k0 = *(const float4*)&kvt[c*8];
    const float4 k1 = *(const float4*)&kvt[c*8+4];
    float wv;
    wv = qs[0][px]*k0.x;
    wv = fmaf(qs[1][px], k0.y, wv);
    wv = fmaf(qs[2][px], k0.z, wv);
    wv = fmaf(qs[3][px], k0.w, wv);
    wv = fmaf(qs[4][px], k1.x, wv);
    wv = fmaf(qs[5][px], k1.y, wv);
    wv = fmaf(qs[6][px], k1.z, wv);
    wv = fmaf(qs[7][px], k1.w, wv);
    ob[(size_t)c*N_ + px] = fmaf(scl[px], wv, xs[c*128 + px]);
  }
}

// ---------------------------------------------------------------------------
extern "C" void kernel_launch(void* const* d_in, const int* in_sizes, int n_in,
                              void* d_out, int out_size, void* d_ws, size_t ws_size,
                              hipStream_t stream) {
  const float* x      = (const float*)d_in[0];
  const float* gamma  = (const float*)d_in[1];
  const float* q_w    = (const float*)d_in[2];
  const float* q_b    = (const float*)d_in[3];
  const float* k_w    = (const float*)d_in[4];
  const float* k_b    = (const float*)d_in[5];
  const float* v_w    = (const float*)d_in[6];
  const float* v_b    = (const float*)d_in[7];
  const float* fc1_w  = (const float*)d_in[8];
  const float* fc1_bn = (const float*)d_in[9];
  const float* c1_w   = (const float*)d_in[10];
  const float* c1_bn  = (const float*)d_in[11];
  const float* c2_w   = (const float*)d_in[12];
  const float* c2_bn  = (const float*)d_in[13];
  const float* fc2_w  = (const float*)d_in[14];
  const float* fc2_bn = (const float*)d_in[15];
  float* outp = (float*)d_out;

  float* ws   = (float*)d_ws;
  float* bufA = ws;                        // h, later reused for V
  float* bufS = ws + (size_t)BCN_;         // s
  float* bufK = ws + (size_t)2*BCN_;       // K (B*M*N)
  float* kv   = ws + (size_t)2*BCN_ + BMN_;
  float* ksum = kv + 2048;

  hipMemsetAsync(kv, 0, (2048 + 32)*sizeof(float), stream);

  k_fc1k<<<dim3(B_*392), dim3(256), 0, stream>>>(x, fc1_w, fc1_bn, k_w, k_b, bufA, bufK);
  k_dw  <<<dim3(B_*C_*49), dim3(256), 0, stream>>>(bufA, c1_w, c2_w, c1_bn, c2_bn, bufS);
  k_v   <<<dim3(B_*392), dim3(256), 0, stream>>>(x, bufS, v_w, v_b, fc2_w, fc2_bn, bufA);
  k_kv  <<<dim3(512), dim3(256), 0, stream>>>(bufA, bufK, kv, ksum);
  k_out <<<dim3(B_*392), dim3(256), 0, stream>>>(x, q_w, q_b, gamma, kv, ksum, outp);
}